// Round 2
// baseline (940.931 us; speedup 1.0000x reference)
//
#include <hip/hip_runtime.h>
#include <hip/hip_bf16.h>
#include <cmath>

// Problem constants: B=64, N=256, IN=128, E=256, H=8, F=1024
#define BB 64
#define NNODES 256
#define INF_ 128
#define EE 256
#define HH 8
#define FFN 1024
#define BNROWS 16384   // B*N

typedef __attribute__((ext_vector_type(8))) short short8;
typedef __attribute__((ext_vector_type(4))) float floatx4;
typedef __attribute__((ext_vector_type(4))) unsigned short ushort4v;

__device__ __forceinline__ float b2f(unsigned short u) {
  union { unsigned u32; float f; } w; w.u32 = ((unsigned)u) << 16; return w.f;
}
__device__ __forceinline__ unsigned short f2b(float f) {
  union { float f; unsigned u32; } w; w.f = f;
  unsigned r = w.u32 + 0x7FFFu + ((w.u32 >> 16) & 1u);   // RNE
  return (unsigned short)(r >> 16);
}

// ---------------------------------------------------------------------------
// f32 -> bf16 conversion (grid-stride over 4-element groups)
// ---------------------------------------------------------------------------
__global__ void cvt_kernel(const float* __restrict__ src,
                           unsigned short* __restrict__ dst, int n)
{
  const int i = (blockIdx.x * 256 + threadIdx.x) * 4;
  if (i >= n) return;
  floatx4 v = *(const floatx4*)(src + i);
  ushort4v o;
  #pragma unroll
  for (int j = 0; j < 4; j++) o[j] = f2b(v[j]);
  *(ushort4v*)(dst + i) = o;
}

// ---------------------------------------------------------------------------
// Generic batched bf16 MFMA GEMM.  C[z] = A[z] (MxK) * B[z] (KxN or NxK if nt)
// Block tile 64x64, BK=32, 256 threads = 4 waves, each wave 2x2 16x16 MFMA.
// All GEMM operands are internal bf16 buffers. mode: 0 = f32 store,
// 1 = bf16 store, 2 = f32 accumulate, 3 = bf16 store of gelu(x+bias[col]).
// M, N multiples of 64; K multiple of 32.
// ---------------------------------------------------------------------------
__launch_bounds__(256)
__global__ void gemm_kernel(const unsigned short* __restrict__ A, long long sA, int lda,
                            const unsigned short* __restrict__ Bm, long long sB, int ldb,
                            void* __restrict__ Cv, long long sC, int ldc,
                            int K, int nt, int mode,
                            const float* __restrict__ bias)
{
  __shared__ __align__(16) unsigned short sAt[64 * 40];
  __shared__ __align__(16) unsigned short sBt[64 * 40];

  const int t = threadIdx.x;
  const int z = blockIdx.z;
  const int m0 = blockIdx.x * 64;
  const int n0 = blockIdx.y * 64;
  A  += (long long)z * sA;
  Bm += (long long)z * sB;

  const int lane = t & 63;
  const int wv = t >> 6;
  const int wm = wv >> 1;       // m half
  const int wn = wv & 1;        // n half
  const int lm = lane & 15;
  const int qd = lane >> 4;     // 0..3

  floatx4 acc00 = {0.f,0.f,0.f,0.f};
  floatx4 acc01 = {0.f,0.f,0.f,0.f};
  floatx4 acc10 = {0.f,0.f,0.f,0.f};
  floatx4 acc11 = {0.f,0.f,0.f,0.f};

  const int arow = t >> 2;            // 0..63
  const int acb  = (t & 3) * 8;       // 0,8,16,24
  const int bc   = t & 63;            // NN transpose staging: column
  const int br0  = (t >> 6) * 8;      // 0,8,16,24

  for (int kk = 0; kk < K; kk += 32) {
    { // A tile: rows m0..m0+63, cols kk..kk+31
      const unsigned short* p = A + (long long)(m0 + arow) * lda + kk + acb;
      short8 v = *(const short8*)p;
      *(short8*)&sAt[arow * 40 + acb] = v;
    }
    if (nt) { // B is (N,K): copy rows like A
      const unsigned short* p = Bm + (long long)(n0 + arow) * ldb + kk + acb;
      short8 v = *(const short8*)p;
      *(short8*)&sBt[arow * 40 + acb] = v;
    } else {  // B is (K,N): transpose into sBt[n][k]
      const unsigned short* p = Bm + (long long)(kk + br0) * ldb + n0 + bc;
      short8 v;
      #pragma unroll
      for (int i = 0; i < 8; i++) v[i] = (short)p[(long long)i * ldb];
      *(short8*)&sBt[bc * 40 + br0] = v;
    }
    __syncthreads();

    short8 a0 = *(const short8*)&sAt[(wm * 32 + lm) * 40 + qd * 8];
    short8 a1 = *(const short8*)&sAt[(wm * 32 + 16 + lm) * 40 + qd * 8];
    short8 b0 = *(const short8*)&sBt[(wn * 32 + lm) * 40 + qd * 8];
    short8 b1 = *(const short8*)&sBt[(wn * 32 + 16 + lm) * 40 + qd * 8];

    acc00 = __builtin_amdgcn_mfma_f32_16x16x32_bf16(a0, b0, acc00, 0, 0, 0);
    acc01 = __builtin_amdgcn_mfma_f32_16x16x32_bf16(a0, b1, acc01, 0, 0, 0);
    acc10 = __builtin_amdgcn_mfma_f32_16x16x32_bf16(a1, b0, acc10, 0, 0, 0);
    acc11 = __builtin_amdgcn_mfma_f32_16x16x32_bf16(a1, b1, acc11, 0, 0, 0);

    __syncthreads();
  }

  const long long cbase = (long long)z * sC;
  #pragma unroll
  for (int mi = 0; mi < 2; mi++) {
    #pragma unroll
    for (int ni = 0; ni < 2; ni++) {
      floatx4 a = mi == 0 ? (ni == 0 ? acc00 : acc01)
                          : (ni == 0 ? acc10 : acc11);
      const int col = n0 + wn * 32 + ni * 16 + lm;
      #pragma unroll
      for (int r = 0; r < 4; r++) {
        const int row = m0 + wm * 32 + mi * 16 + qd * 4 + r;
        const long long ci = cbase + (long long)row * ldc + col;
        const float val = a[r];
        if (mode == 0) {
          ((float*)Cv)[ci] = val;
        } else if (mode == 1) {
          ((unsigned short*)Cv)[ci] = f2b(val);
        } else if (mode == 2) {
          ((float*)Cv)[ci] += val;
        } else { // 3: bias + exact gelu -> bf16
          const float xv = val + bias[col];
          const float g = 0.5f * xv * (1.0f + erff(xv * 0.70710678118654752f));
          ((unsigned short*)Cv)[ci] = f2b(g);
        }
      }
    }
  }
}

// ---------------------------------------------------------------------------
// dis = rsqrt(clip(rowsum(A),1,inf)); A = adj (f32) with diag forced to 1
// wave per row; 4 rows per block.
// ---------------------------------------------------------------------------
__global__ void deg_kernel(const float* __restrict__ adj,
                           float* __restrict__ dis)
{
  const int g = blockIdx.x * 4 + (threadIdx.x >> 6);   // row b*256+i
  const int lane = threadIdx.x & 63;
  const int i = g & 255;
  floatx4 v = *(const floatx4*)(adj + (long long)g * 256 + lane * 4);
  float s = 0.f;
  #pragma unroll
  for (int jj = 0; jj < 4; jj++) {
    const int j = lane * 4 + jj;
    s += (j == i) ? 1.0f : v[jj];
  }
  #pragma unroll
  for (int off = 32; off > 0; off >>= 1) s += __shfl_xor(s, off);
  if (lane == 0) dis[g] = 1.0f / sqrtf(fmaxf(s, 1.0f));
}

// An[b,i,j] = bf16(dis_i * A_ij * dis_j)   (adj f32 -> An bf16)
__global__ void an_kernel(const float* __restrict__ adj,
                          const float* __restrict__ dis,
                          unsigned short* __restrict__ An)
{
  const long long base = ((long long)blockIdx.x * 256 + threadIdx.x) * 4;
  const int rowg = (int)(base >> 8);     // b*256 + i
  const int i = rowg & 255;
  const int brow = rowg & ~255;          // b*256
  const int j0 = (int)(base & 255);
  const float di = dis[rowg];
  floatx4 v = *(const floatx4*)(adj + base);
  ushort4v o;
  #pragma unroll
  for (int jj = 0; jj < 4; jj++) {
    const int j = j0 + jj;
    const float a = (j == i) ? 1.0f : v[jj];
    o[jj] = f2b(di * dis[brow + j] * a);
  }
  *(ushort4v*)(An + base) = o;
}

// g = relu((u + bias[col]) * mask[row]);  Gbf = bf16(g); Gcn (+)= g
__global__ void gcn_epi_kernel(const float* __restrict__ U,
                               const float* __restrict__ bias,
                               const float* __restrict__ mask,
                               unsigned short* __restrict__ Gbf,
                               float* __restrict__ Gcn, int accflag)
{
  const long long base = ((long long)blockIdx.x * 256 + threadIdx.x) * 4;
  const int col = (int)(base & 255);
  const int row = (int)(base >> 8);
  const float m = mask[row];
  floatx4 u = *(const floatx4*)(U + base);
  floatx4 gf;
  ushort4v gb;
  #pragma unroll
  for (int jj = 0; jj < 4; jj++) {
    float xv = (u[jj] + bias[col + jj]) * m;
    xv = fmaxf(xv, 0.f);
    gf[jj] = xv;
    gb[jj] = f2b(xv);
  }
  *(ushort4v*)(Gbf + base) = gb;
  if (accflag) {
    floatx4 old = *(const floatx4*)(Gcn + base);
    gf += old;
  }
  *(floatx4*)(Gcn + base) = gf;
}

// LayerNorm over last dim (256): out_bf16 = (x-mean)*rsqrt(var+1e-5)*g + b
__global__ void ln_kernel(const float* __restrict__ X,
                          const float* __restrict__ gam,
                          const float* __restrict__ bet,
                          unsigned short* __restrict__ out)
{
  const int g = blockIdx.x * 4 + (threadIdx.x >> 6);
  const int lane = threadIdx.x & 63;
  floatx4 v = *(const floatx4*)(X + (long long)g * 256 + lane * 4);
  float s = v[0] + v[1] + v[2] + v[3];
  float sq = v[0]*v[0] + v[1]*v[1] + v[2]*v[2] + v[3]*v[3];
  #pragma unroll
  for (int off = 32; off > 0; off >>= 1) {
    s  += __shfl_xor(s, off);
    sq += __shfl_xor(sq, off);
  }
  const float mean = s * (1.0f / 256.0f);
  const float var = sq * (1.0f / 256.0f) - mean * mean;
  const float rs = 1.0f / sqrtf(var + 1e-5f);
  ushort4v o;
  #pragma unroll
  for (int jj = 0; jj < 4; jj++) {
    const int c = lane * 4 + jj;
    o[jj] = f2b((v[jj] - mean) * rs * gam[c] + bet[c]);
  }
  *(ushort4v*)(out + (long long)g * 256 + lane * 4) = o;
}

// softmax row: val = valid ? s*E^-0.5 + dist : -1e9 ; P = valid ? softmax : 0
__global__ void softmax_kernel(const float* __restrict__ S,
                               const float* __restrict__ dist,
                               const float* __restrict__ mask,
                               unsigned short* __restrict__ P)
{
  const int g = blockIdx.x * 4 + (threadIdx.x >> 6);   // b*256 + i
  const int lane = threadIdx.x & 63;
  const int brow = g & ~255;
  const float mi = mask[g];
  const long long base = (long long)g * 256 + lane * 4;
  floatx4 s4 = *(const floatx4*)(S + base);
  floatx4 d4 = *(const floatx4*)(dist + base);
  float val[4];
  bool vld[4];
  #pragma unroll
  for (int jj = 0; jj < 4; jj++) {
    const int j = lane * 4 + jj;
    const float mj = mask[brow + j];
    vld[jj] = (mi != 0.f) && (mj != 0.f);
    val[jj] = vld[jj] ? (s4[jj] * 0.0625f + d4[jj]) : -1e9f;
  }
  float mx = fmaxf(fmaxf(val[0], val[1]), fmaxf(val[2], val[3]));
  #pragma unroll
  for (int off = 32; off > 0; off >>= 1) mx = fmaxf(mx, __shfl_xor(mx, off));
  float es[4];
  float sum = 0.f;
  #pragma unroll
  for (int jj = 0; jj < 4; jj++) { es[jj] = expf(val[jj] - mx); sum += es[jj]; }
  #pragma unroll
  for (int off = 32; off > 0; off >>= 1) sum += __shfl_xor(sum, off);
  const float inv = 1.0f / sum;
  ushort4v o;
  #pragma unroll
  for (int jj = 0; jj < 4; jj++) o[jj] = vld[jj] ? f2b(es[jj] * inv) : (unsigned short)0;
  *(ushort4v*)(P + base) = o;
}

// ATT = GCN + (O + bo[col]) * mask[row]
__global__ void att_epi_kernel(const float* __restrict__ O,
                               const float* __restrict__ bo,
                               const float* __restrict__ mask,
                               const float* __restrict__ GCN,
                               float* __restrict__ ATT)
{
  const long long base = ((long long)blockIdx.x * 256 + threadIdx.x) * 4;
  const int col = (int)(base & 255);
  const int row = (int)(base >> 8);
  const float m = mask[row];
  floatx4 o = *(const floatx4*)(O + base);
  floatx4 gcn = *(const floatx4*)(GCN + base);
  floatx4 r;
  #pragma unroll
  for (int jj = 0; jj < 4; jj++) r[jj] = gcn[jj] + (o[jj] + bo[col + jj]) * m;
  *(floatx4*)(ATT + base) = r;
}

// out(f32) = GCN + ATT + (W + bf2[col]) * mask[row]
__global__ void final_kernel(const float* __restrict__ Wf,
                             const float* __restrict__ bf2,
                             const float* __restrict__ mask,
                             const float* __restrict__ GCN,
                             const float* __restrict__ ATT,
                             float* __restrict__ out)
{
  const long long base = ((long long)blockIdx.x * 256 + threadIdx.x) * 4;
  const int col = (int)(base & 255);
  const int row = (int)(base >> 8);
  const float m = mask[row];
  floatx4 wv = *(const floatx4*)(Wf + base);
  floatx4 gcn = *(const floatx4*)(GCN + base);
  floatx4 att = *(const floatx4*)(ATT + base);
  floatx4 r;
  #pragma unroll
  for (int jj = 0; jj < 4; jj++)
    r[jj] = gcn[jj] + att[jj] + (wv[jj] + bf2[col + jj]) * m;
  *(floatx4*)(out + base) = r;
}

// ---------------------------------------------------------------------------
static inline void launch_gemm(hipStream_t st,
    const void* A, long long sA, int lda,
    const void* Bm, long long sB, int ldb,
    void* C, long long sC, int ldc,
    int M, int N, int K, int batch, int nt, int mode, const float* bias)
{
  dim3 grid(M / 64, N / 64, batch), blk(256);
  gemm_kernel<<<grid, blk, 0, st>>>(
      (const unsigned short*)A, sA, lda,
      (const unsigned short*)Bm, sB, ldb,
      C, sC, ldc, K, nt, mode, bias);
}

extern "C" void kernel_launch(void* const* d_in, const int* in_sizes, int n_in,
                              void* d_out, int out_size, void* d_ws, size_t ws_size,
                              hipStream_t stream)
{
  (void)in_sizes; (void)n_in; (void)out_size;
  const float* x    = (const float*)d_in[0];
  const float* adj  = (const float*)d_in[1];
  const float* mask = (const float*)d_in[2];
  const float* dist = (const float*)d_in[3];
  const float* W1   = (const float*)d_in[4];
  const float* b1   = (const float*)d_in[5];
  const float* W2   = (const float*)d_in[6];
  const float* b2   = (const float*)d_in[7];
  const float* W3   = (const float*)d_in[8];
  const float* b3   = (const float*)d_in[9];
  const float* ln1g = (const float*)d_in[10];
  const float* ln1b = (const float*)d_in[11];
  const float* Wq   = (const float*)d_in[12];
  const float* Wk   = (const float*)d_in[13];
  const float* Wv   = (const float*)d_in[14];
  const float* Wo   = (const float*)d_in[15];
  const float* bo   = (const float*)d_in[16];
  const float* ln2g = (const float*)d_in[17];
  const float* ln2b = (const float*)d_in[18];
  const float* Wf1  = (const float*)d_in[19];
  const float* bf1  = (const float*)d_in[20];
  const float* Wf2  = (const float*)d_in[21];
  const float* bf2  = (const float*)d_in[22];

  char* w = (char*)d_ws;
  auto alloc = [&](size_t sz) { void* p = (void*)w; w += sz; return p; };
  float*          DIS  = (float*)         alloc(65536);        // 16384 f32
  unsigned short* AN   = (unsigned short*)alloc(8388608);      // (B,256,256) bf16
  unsigned short* XBF  = (unsigned short*)alloc(4194304);      // (BN,128) bf16
  unsigned short* WB   = (unsigned short*)alloc(5570560);      // packed bf16 weights
  unsigned short* TBF  = (unsigned short*)alloc(8388608);      // (BN,256) bf16 (also YH)
  float*          U    = (float*)         alloc(16777216);     // (BN,256) f32
  unsigned short* GBF  = (unsigned short*)alloc(8388608);      // (also PBF)
  float*          GCN  = (float*)         alloc(16777216);
  unsigned short* HBF  = (unsigned short*)alloc(8388608);
  unsigned short* QH   = (unsigned short*)alloc(8388608);      // per-head q (contig q,k,v)
  unsigned short* KH   = (unsigned short*)alloc(8388608);
  unsigned short* VH   = (unsigned short*)alloc(8388608);
  float*          S    = (float*)         alloc(16777216);     // per-head scores
  float*          ATT  = (float*)         alloc(16777216);
  unsigned short* FFB  = (unsigned short*)alloc(33554432);     // (BN,1024) bf16
  if ((size_t)(w - (char*)d_ws) > ws_size) return;             // ws too small
  (void)KH; (void)VH;                                          // addressed via QH strides
  unsigned short* YH  = TBF;                                   // reuse after GCN stack
  unsigned short* PBF = GBF;                                   // reuse after GCN stack

  // packed weight layout inside WB (element offsets)
  unsigned short* W1b   = WB;                  // 32768
  unsigned short* W2b   = WB + 32768;          // 65536
  unsigned short* W3b   = WB + 98304;          // 65536
  unsigned short* WQKVb = WB + 163840;         // 3 x 524288 (q|k|v, each (256,2048))
  unsigned short* WOb   = WB + 1736704;        // 524288    (2048,256)
  unsigned short* WF1b  = WB + 2260992;        // 262144    (256,1024)
  unsigned short* WF2b  = WB + 2523136;        // 262144    (1024,256)

  auto cvt = [&](const float* s, unsigned short* d, int n) {
    cvt_kernel<<<(n / 4 + 255) / 256, 256, 0, stream>>>(s, d, n);
  };
  cvt(x,  XBF, BNROWS * INF_);
  cvt(W1, W1b, INF_ * EE);
  cvt(W2, W2b, EE * EE);
  cvt(W3, W3b, EE * EE);
  cvt(Wq, WQKVb,           EE * HH * EE);
  cvt(Wk, WQKVb + 524288,  EE * HH * EE);
  cvt(Wv, WQKVb + 1048576, EE * HH * EE);
  cvt(Wo, WOb,  HH * EE * EE);
  cvt(Wf1, WF1b, EE * FFN);
  cvt(Wf2, WF2b, FFN * EE);

  // ---- adjacency normalization ----
  deg_kernel<<<4096, 256, 0, stream>>>(adj, DIS);
  an_kernel<<<4096, 256, 0, stream>>>(adj, DIS, AN);

  // ---- GCN stack ----
  launch_gemm(stream, XBF, 0, INF_, W1b, 0, EE, TBF, 0, EE, BNROWS, EE, INF_, 1, 0, 1, nullptr);
  launch_gemm(stream, AN, 65536, NNODES, TBF, 65536, EE, U, 65536, EE, NNODES, EE, NNODES, BB, 0, 0, nullptr);
  gcn_epi_kernel<<<4096, 256, 0, stream>>>(U, b1, mask, GBF, GCN, 0);

  launch_gemm(stream, GBF, 0, EE, W2b, 0, EE, TBF, 0, EE, BNROWS, EE, EE, 1, 0, 1, nullptr);
  launch_gemm(stream, AN, 65536, NNODES, TBF, 65536, EE, U, 65536, EE, NNODES, EE, NNODES, BB, 0, 0, nullptr);
  gcn_epi_kernel<<<4096, 256, 0, stream>>>(U, b2, mask, GBF, GCN, 1);

  launch_gemm(stream, GBF, 0, EE, W3b, 0, EE, TBF, 0, EE, BNROWS, EE, EE, 1, 0, 1, nullptr);
  launch_gemm(stream, AN, 65536, NNODES, TBF, 65536, EE, U, 65536, EE, NNODES, EE, NNODES, BB, 0, 0, nullptr);
  gcn_epi_kernel<<<4096, 256, 0, stream>>>(U, b3, mask, GBF, GCN, 1);

  // ---- LN1 ----
  ln_kernel<<<4096, 256, 0, stream>>>(GCN, ln1g, ln1b, HBF);

  // ---- attention (per head; q/k/v token-masking is mathematically redundant
  //      given score masking + P-zeroing + final m3, so it is skipped) ----
  for (int h = 0; h < HH; h++) {
    // q,k,v in one batched launch (z: 0->QH, 1->KH, 2->VH, contiguous allocs)
    launch_gemm(stream, HBF, 0, EE, WQKVb + h * EE, 524288, HH * EE,
                QH, 4194304, EE, BNROWS, EE, EE, 3, 0, 1, nullptr);
    // scores = q k^T (NT), raw f32 (scale+dist applied in softmax)
    launch_gemm(stream, QH, 65536, EE, QH + 4194304, 65536, EE, S, 65536, NNODES,
                NNODES, NNODES, EE, BB, 1, 0, nullptr);
    softmax_kernel<<<4096, 256, 0, stream>>>(S, dist, mask, PBF);
    // y = P v
    launch_gemm(stream, PBF, 65536, NNODES, QH + 8388608, 65536, EE, YH, 65536, EE,
                NNODES, EE, NNODES, BB, 0, 1, nullptr);
    // o (+)= y @ Wo_h
    launch_gemm(stream, YH, 0, EE, WOb + h * EE * EE, 0, EE, U, 0, EE,
                BNROWS, EE, EE, 1, 0, (h == 0 ? 0 : 2), nullptr);
  }

  // ---- residual + LN2 + FFN ----
  att_epi_kernel<<<4096, 256, 0, stream>>>(U, bo, mask, GCN, ATT);
  ln_kernel<<<4096, 256, 0, stream>>>(ATT, ln2g, ln2b, HBF);
  launch_gemm(stream, HBF, 0, EE, WF1b, 0, FFN, FFB, 0, FFN,
              BNROWS, FFN, EE, 1, 0, 3, bf1);
  launch_gemm(stream, FFB, 0, FFN, WF2b, 0, EE, U, 0, EE,
              BNROWS, EE, FFN, 1, 0, 0, nullptr);
  final_kernel<<<4096, 256, 0, stream>>>(U, bf2, mask, GCN, ATT,
                                         (float*)d_out);
}

// Round 3
// 879.554 us; speedup vs baseline: 1.0698x; 1.0698x over previous
//
#include <hip/hip_runtime.h>
#include <hip/hip_bf16.h>
#include <cmath>

// Problem constants: B=64, N=256, IN=128, E=256, H=8, F=1024
#define BB 64
#define NNODES 256
#define INF_ 128
#define EE 256
#define HH 8
#define FFN 1024
#define BNROWS 16384   // B*N

typedef __attribute__((ext_vector_type(8))) short short8;
typedef __attribute__((ext_vector_type(4))) float floatx4;
typedef __attribute__((ext_vector_type(4))) unsigned short ushort4v;

__device__ __forceinline__ float b2f(unsigned short u) {
  union { unsigned u32; float f; } w; w.u32 = ((unsigned)u) << 16; return w.f;
}
__device__ __forceinline__ unsigned short f2b(float f) {
  union { float f; unsigned u32; } w; w.f = f;
  unsigned r = w.u32 + 0x7FFFu + ((w.u32 >> 16) & 1u);   // RNE
  return (unsigned short)(r >> 16);
}

typedef const __attribute__((address_space(1))) void GV;
typedef __attribute__((address_space(3))) void LV;

// async global->LDS, 16B/lane; lds base must be wave-uniform (HW: base+lane*16)
__device__ __forceinline__ void gl_lds16(const unsigned short* g,
                                         unsigned short* l, int lane) {
#if __has_builtin(__builtin_amdgcn_global_load_lds)
  __builtin_amdgcn_global_load_lds((GV*)g, (LV*)l, 16, 0, 0);
#else
  *(short8*)(l + lane * 8) = *(const short8*)g;
#endif
}

// ---------------------------------------------------------------------------
// f32 -> bf16 conversion (contiguous)
// ---------------------------------------------------------------------------
__global__ void cvt_kernel(const float* __restrict__ src,
                           unsigned short* __restrict__ dst, int n)
{
  const int i = (blockIdx.x * 256 + threadIdx.x) * 4;
  if (i >= n) return;
  floatx4 v = *(const floatx4*)(src + i);
  ushort4v o;
  #pragma unroll
  for (int j = 0; j < 4; j++) o[j] = f2b(v[j]);
  *(ushort4v*)(dst + i) = o;
}

// ---------------------------------------------------------------------------
// Tiled transpose + f32->bf16: dst[c][r] = bf16(src[r][c]); src (R x C).
// slot >= 0 remaps output row c -> (c>>9)*1536 + slot*512 + (c&511)  (QKV pack)
// grid (C/32, R/32), block (32,8)
// ---------------------------------------------------------------------------
__global__ void tcvt_kernel(const float* __restrict__ src,
                            unsigned short* __restrict__ dst,
                            int R, int C, int slot)
{
  __shared__ float tile[32][33];
  const int c0 = blockIdx.x * 32, r0 = blockIdx.y * 32;
  const int tx = threadIdx.x, ty = threadIdx.y;
  #pragma unroll
  for (int i = ty; i < 32; i += 8)
    tile[i][tx] = src[(long long)(r0 + i) * C + c0 + tx];
  __syncthreads();
  #pragma unroll
  for (int i = ty; i < 32; i += 8) {
    const int c = c0 + i;
    const int dr = (slot < 0) ? c : ((c >> 9) * 1536 + slot * 512 + (c & 511));
    dst[(long long)dr * R + r0 + tx] = f2b(tile[tx][i]);
  }
}

// ---------------------------------------------------------------------------
// Generic batched bf16 MFMA GEMM, 128x128 tile, BK=32, global_load_lds.
// A (M,K) row-major; B given as (N,K) row-major (always "NT").
// LDS layout (k-blocked, conflict-free): elem(r,k) at (k>>3)*1024 + r*8 + (k&7)
// z = blockIdx.z decomposed: zi = z & ((1<<zshift)-1), zb = z >> zshift.
// modes:
//  0: f32 store C[row*ldc+col]
//  1: bf16 store
//  2: f32 accumulate
//  3: bf16 store of gelu(val + aux1[col])
//  5: "TT" store: b=row>>8, n=row&255 -> bf16 C[b*65536 + col*256 + n]
//  7: scores: bf16 C[cb+row*ldc+col] = val*0.0625 + aux1[zb*65536+row*256+col]
//  8: final:  f32 C[row*256+col] = gcn[i] + attf[i] + (val+aux1[col])*mask[row]
//  9: GCN epi (C'=U^T): token=zb*256+col, feat=row; g=relu((val+aux1[feat])*mask[token]);
//     bf16 C[token*256+feat]=g; gcn[token*256+feat] (flag? += : =) g
// 11: QKV split: col<1024 -> bf16 C normal; else V^T: z2=(row>>8)*2+((col-1024)>>8),
//     bf16 aux2u[z2*65536 + (col&255)*256 + (row&255)]
// ---------------------------------------------------------------------------
__launch_bounds__(256)
__global__ void gemm_kernel(const unsigned short* __restrict__ A, int lda,
                            long long sAo, long long sAi,
                            const unsigned short* __restrict__ Bm, int ldb,
                            long long sBo, long long sBi,
                            void* __restrict__ Cv, int ldc,
                            long long sCo, long long sCi,
                            int K, int zshift, int mode, int flag,
                            const float* __restrict__ aux1,
                            const float* __restrict__ mask,
                            float* __restrict__ gcn,
                            void* __restrict__ aux2)
{
  __shared__ __align__(16) unsigned short sA[4096];
  __shared__ __align__(16) unsigned short sB[4096];

  const int t = threadIdx.x;
  const int z = blockIdx.z;
  const int zi = z & ((1 << zshift) - 1);
  const int zb = z >> zshift;
  const int m0 = blockIdx.x * 128;
  const int n0 = blockIdx.y * 128;
  A  += zb * sAo + zi * sAi;
  Bm += zb * sBo + zi * sBi;
  const long long cbase = zb * sCo + zi * sCi;

  const int lane = t & 63;
  const int w = t >> 6;            // wave 0..3
  const int wm = w >> 1, wn = w & 1;
  const int lm = lane & 15, qd = lane >> 4;

  floatx4 acc[4][4] = {};

  // staging: wave w owns k-block qb=w (k = w*8 .. w*8+7 within the BK=32 tile)
  const unsigned short* gA0 = A + (long long)(m0 + lane) * lda + w * 8;
  const unsigned short* gA1 = gA0 + (long long)64 * lda;
  const unsigned short* gB0 = Bm + (long long)(n0 + lane) * ldb + w * 8;
  const unsigned short* gB1 = gB0 + (long long)64 * ldb;
  unsigned short* lA0 = &sA[w * 1024];
  unsigned short* lA1 = &sA[w * 1024 + 512];
  unsigned short* lB0 = &sB[w * 1024];
  unsigned short* lB1 = &sB[w * 1024 + 512];

  for (int kk = 0; kk < K; kk += 32) {
    gl_lds16(gA0 + kk, lA0, lane);
    gl_lds16(gA1 + kk, lA1, lane);
    gl_lds16(gB0 + kk, lB0, lane);
    gl_lds16(gB1 + kk, lB1, lane);
    __syncthreads();   // compiler emits vmcnt(0) drain before barrier

    short8 af[4], bg[4];
    #pragma unroll
    for (int i = 0; i < 4; i++) {
      af[i] = *(const short8*)&sA[qd * 1024 + (wm * 64 + i * 16 + lm) * 8];
      bg[i] = *(const short8*)&sB[qd * 1024 + (wn * 64 + i * 16 + lm) * 8];
    }
    #pragma unroll
    for (int mi = 0; mi < 4; mi++)
      #pragma unroll
      for (int ni = 0; ni < 4; ni++)
        acc[mi][ni] = __builtin_amdgcn_mfma_f32_16x16x32_bf16(
            af[mi], bg[ni], acc[mi][ni], 0, 0, 0);
    __syncthreads();
  }

  // ---- epilogue ----
  #pragma unroll
  for (int mi = 0; mi < 4; mi++) {
    const int row0 = m0 + wm * 64 + mi * 16 + qd * 4;
    #pragma unroll
    for (int ni = 0; ni < 4; ni++) {
      const int col = n0 + wn * 64 + ni * 16 + lm;
      floatx4 a = acc[mi][ni];
      if (mode == 0) {
        float* Cf = (float*)Cv;
        #pragma unroll
        for (int r = 0; r < 4; r++)
          Cf[cbase + (long long)(row0 + r) * ldc + col] = a[r];
      } else if (mode == 1) {
        unsigned short* Cb = (unsigned short*)Cv;
        #pragma unroll
        for (int r = 0; r < 4; r++)
          Cb[cbase + (long long)(row0 + r) * ldc + col] = f2b(a[r]);
      } else if (mode == 2) {
        float* Cf = (float*)Cv;
        #pragma unroll
        for (int r = 0; r < 4; r++)
          Cf[cbase + (long long)(row0 + r) * ldc + col] += a[r];
      } else if (mode == 3) {
        unsigned short* Cb = (unsigned short*)Cv;
        const float bv = aux1[col];
        #pragma unroll
        for (int r = 0; r < 4; r++) {
          const float xv = a[r] + bv;
          const float g = 0.5f * xv * (1.0f + erff(xv * 0.70710678118654752f));
          Cb[cbase + (long long)(row0 + r) * ldc + col] = f2b(g);
        }
      } else if (mode == 5) {
        const int b = row0 >> 8, n = row0 & 255;
        ushort4v o;
        #pragma unroll
        for (int r = 0; r < 4; r++) o[r] = f2b(a[r]);
        *(ushort4v*)((unsigned short*)Cv + (long long)b * 65536 + col * 256 + n) = o;
      } else if (mode == 7) {
        unsigned short* Cb = (unsigned short*)Cv;
        #pragma unroll
        for (int r = 0; r < 4; r++) {
          const float d = aux1[(long long)zb * 65536 + (row0 + r) * 256 + col];
          Cb[cbase + (long long)(row0 + r) * ldc + col] = f2b(a[r] * 0.0625f + d);
        }
      } else if (mode == 8) {
        float* Cf = (float*)Cv;
        const float* attf = (const float*)aux2;
        const float bv = aux1[col];
        #pragma unroll
        for (int r = 0; r < 4; r++) {
          const long long idx = (long long)(row0 + r) * 256 + col;
          Cf[idx] = gcn[idx] + attf[idx] + (a[r] + bv) * mask[row0 + r];
        }
      } else if (mode == 9) {
        const int token = zb * 256 + col;
        const float m = mask[token];
        ushort4v o; floatx4 g;
        #pragma unroll
        for (int r = 0; r < 4; r++) {
          const float v = fmaxf((a[r] + aux1[row0 + r]) * m, 0.f);
          o[r] = f2b(v); g[r] = v;
        }
        *(ushort4v*)((unsigned short*)Cv + (long long)token * 256 + row0) = o;
        float* gp = gcn + (long long)token * 256 + row0;
        if (flag) { floatx4 old = *(const floatx4*)gp; g += old; }
        *(floatx4*)gp = g;
      } else { // 11
        if (n0 < 1024) {
          unsigned short* Cb = (unsigned short*)Cv;
          #pragma unroll
          for (int r = 0; r < 4; r++)
            Cb[cbase + (long long)(row0 + r) * ldc + col] = f2b(a[r]);
        } else {
          const int z2 = (row0 >> 8) * 2 + ((col - 1024) >> 8);
          const int e = col & 255, n = row0 & 255;
          ushort4v o;
          #pragma unroll
          for (int r = 0; r < 4; r++) o[r] = f2b(a[r]);
          *(ushort4v*)((unsigned short*)aux2 + (long long)z2 * 65536 + e * 256 + n) = o;
        }
      }
    }
  }
}

// ---------------------------------------------------------------------------
// dis = rsqrt(clip(rowsum(A),1,inf)); A = adj (f32) with diag forced to 1
// ---------------------------------------------------------------------------
__global__ void deg_kernel(const float* __restrict__ adj,
                           float* __restrict__ dis)
{
  const int g = blockIdx.x * 4 + (threadIdx.x >> 6);
  const int lane = threadIdx.x & 63;
  const int i = g & 255;
  floatx4 v = *(const floatx4*)(adj + (long long)g * 256 + lane * 4);
  float s = 0.f;
  #pragma unroll
  for (int jj = 0; jj < 4; jj++) {
    const int j = lane * 4 + jj;
    s += (j == i) ? 1.0f : v[jj];
  }
  #pragma unroll
  for (int off = 32; off > 0; off >>= 1) s += __shfl_xor(s, off);
  if (lane == 0) dis[g] = 1.0f / sqrtf(fmaxf(s, 1.0f));
}

// An[b,i,j] = bf16(dis_i * A_ij * dis_j)  (exactly symmetric)
__global__ void an_kernel(const float* __restrict__ adj,
                          const float* __restrict__ dis,
                          unsigned short* __restrict__ An)
{
  const long long base = ((long long)blockIdx.x * 256 + threadIdx.x) * 4;
  const int rowg = (int)(base >> 8);
  const int i = rowg & 255;
  const int brow = rowg & ~255;
  const int j0 = (int)(base & 255);
  const float di = dis[rowg];
  floatx4 v = *(const floatx4*)(adj + base);
  ushort4v o;
  #pragma unroll
  for (int jj = 0; jj < 4; jj++) {
    const int j = j0 + jj;
    const float a = (j == i) ? 1.0f : v[jj];
    o[jj] = f2b(di * dis[brow + j] * a);
  }
  *(ushort4v*)(An + base) = o;
}

// LayerNorm over last dim (256): out_bf16 = (x-mean)*rsqrt(var+1e-5)*g + b
__global__ void ln_kernel(const float* __restrict__ X,
                          const float* __restrict__ gam,
                          const float* __restrict__ bet,
                          unsigned short* __restrict__ out)
{
  const int g = blockIdx.x * 4 + (threadIdx.x >> 6);
  const int lane = threadIdx.x & 63;
  floatx4 v = *(const floatx4*)(X + (long long)g * 256 + lane * 4);
  float s = v[0] + v[1] + v[2] + v[3];
  float sq = v[0]*v[0] + v[1]*v[1] + v[2]*v[2] + v[3]*v[3];
  #pragma unroll
  for (int off = 32; off > 0; off >>= 1) {
    s  += __shfl_xor(s, off);
    sq += __shfl_xor(sq, off);
  }
  const float mean = s * (1.0f / 256.0f);
  const float var = sq * (1.0f / 256.0f) - mean * mean;
  const float rs = 1.0f / sqrtf(var + 1e-5f);
  ushort4v o;
  #pragma unroll
  for (int jj = 0; jj < 4; jj++) {
    const int c = lane * 4 + jj;
    o[jj] = f2b((v[jj] - mean) * rs * gam[c] + bet[c]);
  }
  *(ushort4v*)(out + (long long)g * 256 + lane * 4) = o;
}

// in-place masked softmax on bf16 scores; row g = z*256+i, z=(b*2+h')
__global__ void softmax_kernel(unsigned short* __restrict__ S,
                               const float* __restrict__ mask)
{
  const int g = blockIdx.x * 4 + (threadIdx.x >> 6);
  const int lane = threadIdx.x & 63;
  const int b = g >> 9;
  const int i = g & 255;
  const float mi = mask[b * 256 + i];
  const long long base = (long long)g * 256 + lane * 4;
  ushort4v s4 = *(const ushort4v*)(S + base);
  float val[4]; bool vld[4];
  #pragma unroll
  for (int jj = 0; jj < 4; jj++) {
    const int j = lane * 4 + jj;
    const float mj = mask[b * 256 + j];
    vld[jj] = (mi != 0.f) && (mj != 0.f);
    val[jj] = vld[jj] ? b2f(s4[jj]) : -1e9f;
  }
  float mx = fmaxf(fmaxf(val[0], val[1]), fmaxf(val[2], val[3]));
  #pragma unroll
  for (int off = 32; off > 0; off >>= 1) mx = fmaxf(mx, __shfl_xor(mx, off));
  float es[4]; float sum = 0.f;
  #pragma unroll
  for (int jj = 0; jj < 4; jj++) { es[jj] = expf(val[jj] - mx); sum += es[jj]; }
  #pragma unroll
  for (int off = 32; off > 0; off >>= 1) sum += __shfl_xor(sum, off);
  const float inv = 1.0f / sum;
  ushort4v o;
  #pragma unroll
  for (int jj = 0; jj < 4; jj++)
    o[jj] = vld[jj] ? f2b(es[jj] * inv) : (unsigned short)0;
  *(ushort4v*)(S + base) = o;
}

// in-place: U = GCN + (U + bo[col]) * mask[row]
__global__ void att_epi_kernel(float* U,
                               const float* __restrict__ bo,
                               const float* __restrict__ mask,
                               const float* __restrict__ GCN)
{
  const long long base = ((long long)blockIdx.x * 256 + threadIdx.x) * 4;
  const int col = (int)(base & 255);
  const int row = (int)(base >> 8);
  const float m = mask[row];
  floatx4 o = *(const floatx4*)(U + base);
  floatx4 g = *(const floatx4*)(GCN + base);
  floatx4 r;
  #pragma unroll
  for (int jj = 0; jj < 4; jj++) r[jj] = g[jj] + (o[jj] + bo[col + jj]) * m;
  *(floatx4*)(U + base) = r;
}

// ---------------------------------------------------------------------------
static inline void launch_gemm(hipStream_t st, int M, int N, int batch,
    const void* A, int lda, long long sAo, long long sAi,
    const void* B, int ldb, long long sBo, long long sBi,
    void* C, int ldc, long long sCo, long long sCi,
    int K, int zshift, int mode, int flag,
    const float* aux1, const float* mask, float* gcn, void* aux2)
{
  dim3 grid(M / 128, N / 128, batch), blk(256);
  gemm_kernel<<<grid, blk, 0, st>>>(
      (const unsigned short*)A, lda, sAo, sAi,
      (const unsigned short*)B, ldb, sBo, sBi,
      C, ldc, sCo, sCi, K, zshift, mode, flag, aux1, mask, gcn, aux2);
}

extern "C" void kernel_launch(void* const* d_in, const int* in_sizes, int n_in,
                              void* d_out, int out_size, void* d_ws, size_t ws_size,
                              hipStream_t stream)
{
  (void)in_sizes; (void)n_in; (void)out_size;
  const float* x    = (const float*)d_in[0];
  const float* adj  = (const float*)d_in[1];
  const float* mask = (const float*)d_in[2];
  const float* dist = (const float*)d_in[3];
  const float* W1   = (const float*)d_in[4];
  const float* b1   = (const float*)d_in[5];
  const float* W2   = (const float*)d_in[6];
  const float* b2   = (const float*)d_in[7];
  const float* W3   = (const float*)d_in[8];
  const float* b3   = (const float*)d_in[9];
  const float* ln1g = (const float*)d_in[10];
  const float* ln1b = (const float*)d_in[11];
  const float* Wq   = (const float*)d_in[12];
  const float* Wk   = (const float*)d_in[13];
  const float* Wv   = (const float*)d_in[14];
  const float* Wo   = (const float*)d_in[15];
  const float* bo   = (const float*)d_in[16];
  const float* ln2g = (const float*)d_in[17];
  const float* ln2b = (const float*)d_in[18];
  const float* Wf1  = (const float*)d_in[19];
  const float* bf1  = (const float*)d_in[20];
  const float* Wf2  = (const float*)d_in[21];
  const float* bf2  = (const float*)d_in[22];

  char* w = (char*)d_ws;
  auto alloc = [&](size_t sz) { void* p = (void*)w; w += sz; return p; };
  // persistent
  unsigned short* W1T   = (unsigned short*)alloc(65536);      // (256,128)
  unsigned short* W2T   = (unsigned short*)alloc(131072);     // (256,256)
  unsigned short* W3T   = (unsigned short*)alloc(131072);
  unsigned short* WQKVT = (unsigned short*)alloc(3145728);    // (6144,256) grouped
  unsigned short* WOT   = (unsigned short*)alloc(1048576);    // (256,2048)
  unsigned short* WF1T  = (unsigned short*)alloc(524288);     // (1024,256)
  unsigned short* WF2T  = (unsigned short*)alloc(524288);     // (256,1024)
  unsigned short* XBF   = (unsigned short*)alloc(4194304);    // (16384,128)
  float*          GCN   = (float*)         alloc(16777216);   // (16384,256) f32
  float*          U     = (float*)         alloc(16777216);   // O accum / ATT
  unsigned short* HBF   = (unsigned short*)alloc(8388608);    // (16384,256) bf16
  float*          DIS   = (float*)         alloc(65536);
  // scratch union (max of the three phases = attention phase, 100.7 MB)
  char* scratch = (char*)alloc(100663296);
  if ((size_t)(w - (char*)d_ws) > ws_size) return;
  // gcn phase views
  unsigned short* AN  = (unsigned short*)scratch;              // 8.4 MB
  unsigned short* TT  = (unsigned short*)(scratch + 8388608);  // 8.4 MB
  unsigned short* GBF = (unsigned short*)(scratch + 16777216); // 8.4 MB
  // attention phase views
  unsigned short* QKVG = (unsigned short*)scratch;                 // 50.3 MB
  unsigned short* VT   = (unsigned short*)(scratch + 50331648);    // 16.8 MB
  unsigned short* S    = (unsigned short*)(scratch + 67108864);    // 16.8 MB
  unsigned short* YG   = (unsigned short*)(scratch + 83886080);    // 16.8 MB
  // ffn phase view
  unsigned short* FFB  = (unsigned short*)scratch;                 // 33.6 MB

  // ---- weight packing (transpose + cvt) ----
  dim3 tb(32, 8);
  tcvt_kernel<<<dim3(8, 4),  tb, 0, stream>>>(W1,  W1T,  128,  256, -1);
  tcvt_kernel<<<dim3(8, 8),  tb, 0, stream>>>(W2,  W2T,  256,  256, -1);
  tcvt_kernel<<<dim3(8, 8),  tb, 0, stream>>>(W3,  W3T,  256,  256, -1);
  tcvt_kernel<<<dim3(64, 8), tb, 0, stream>>>(Wq,  WQKVT, 256, 2048, 0);
  tcvt_kernel<<<dim3(64, 8), tb, 0, stream>>>(Wk,  WQKVT, 256, 2048, 1);
  tcvt_kernel<<<dim3(64, 8), tb, 0, stream>>>(Wv,  WQKVT, 256, 2048, 2);
  tcvt_kernel<<<dim3(8, 64), tb, 0, stream>>>(Wo,  WOT,  2048,  256, -1);
  tcvt_kernel<<<dim3(32, 8), tb, 0, stream>>>(Wf1, WF1T,  256, 1024, -1);
  tcvt_kernel<<<dim3(8, 32), tb, 0, stream>>>(Wf2, WF2T, 1024,  256, -1);
  cvt_kernel<<<2048, 256, 0, stream>>>(x, XBF, BNROWS * INF_);

  // ---- adjacency normalization ----
  deg_kernel<<<4096, 256, 0, stream>>>(adj, DIS);
  an_kernel<<<4096, 256, 0, stream>>>(adj, DIS, AN);

  // ---- GCN stack: W-GEMM stores T^T (mode 5); An-GEMM (B=An, symmetric)
  //      computes U^T with fused bias+mask+relu+GCN-accum epilogue (mode 9)
  launch_gemm(stream, BNROWS, EE, 1, XBF, 128, 0,0, W1T, 128, 0,0,
              TT, 256, 0,0, 128, 0, 5, 0, nullptr, nullptr, nullptr, nullptr);
  launch_gemm(stream, 256, 256, BB, TT, 256, 65536,0, AN, 256, 65536,0,
              GBF, 256, 0,0, 256, 0, 9, 0, b1, mask, GCN, nullptr);
  launch_gemm(stream, BNROWS, EE, 1, GBF, 256, 0,0, W2T, 256, 0,0,
              TT, 256, 0,0, 256, 0, 5, 0, nullptr, nullptr, nullptr, nullptr);
  launch_gemm(stream, 256, 256, BB, TT, 256, 65536,0, AN, 256, 65536,0,
              GBF, 256, 0,0, 256, 0, 9, 1, b2, mask, GCN, nullptr);
  launch_gemm(stream, BNROWS, EE, 1, GBF, 256, 0,0, W3T, 256, 0,0,
              TT, 256, 0,0, 256, 0, 5, 0, nullptr, nullptr, nullptr, nullptr);
  launch_gemm(stream, 256, 256, BB, TT, 256, 65536,0, AN, 256, 65536,0,
              GBF, 256, 0,0, 256, 0, 9, 1, b3, mask, GCN, nullptr);

  // ---- LN1 ----
  ln_kernel<<<4096, 256, 0, stream>>>(GCN, ln1g, ln1b, HBF);

  // ---- attention: 4 groups of 2 heads ----
  for (int g = 0; g < 4; g++) {
    // QKV for 2 heads: C cols 0-511 q, 512-1023 k; v stored transposed to VT
    launch_gemm(stream, BNROWS, 1536, 1, HBF, 256, 0,0,
                WQKVT + (long long)g * 1536 * 256, 256, 0,0,
                QKVG, 1536, 0,0, 256, 0, 11, 0, nullptr, nullptr, nullptr, VT);
    // scores (z = b*2+h'): bf16 S = qk*0.0625 + dist  (mask applied in softmax)
    launch_gemm(stream, 256, 256, 128, QKVG, 1536, 393216, 256,
                QKVG + 512, 1536, 393216, 256,
                S, 256, 131072, 65536, 256, 1, 7, 0, dist, nullptr, nullptr, nullptr);
    softmax_kernel<<<8192, 256, 0, stream>>>(S, mask);
    // y = P v   (B = V^T, NT)
    launch_gemm(stream, 256, 256, 128, S, 256, 131072, 65536,
                VT, 256, 131072, 65536,
                YG, 512, 131072, 256, 256, 1, 1, 0, nullptr, nullptr, nullptr, nullptr);
    // O (+)= Y_g @ Wo_g
    launch_gemm(stream, BNROWS, EE, 1, YG, 512, 0,0,
                WOT + g * 512, 2048, 0,0,
                U, 256, 0,0, 512, 0, (g == 0 ? 0 : 2), 0,
                nullptr, nullptr, nullptr, nullptr);
  }

  // ---- residual + LN2 + FFN (final residual fused into FFN2 epilogue) ----
  att_epi_kernel<<<4096, 256, 0, stream>>>(U, bo, mask, GCN);
  ln_kernel<<<4096, 256, 0, stream>>>(U, ln2g, ln2b, HBF);
  launch_gemm(stream, BNROWS, FFN, 1, HBF, 256, 0,0, WF1T, 256, 0,0,
              FFB, 1024, 0,0, 256, 0, 3, 0, bf1, nullptr, nullptr, nullptr);
  launch_gemm(stream, BNROWS, EE, 1, FFB, 1024, 0,0, WF2T, 1024, 0,0,
              d_out, 256, 0,0, 1024, 0, 8, 0, bf2, mask, GCN, U);
}

// Round 4
// 663.689 us; speedup vs baseline: 1.4177x; 1.3252x over previous
//
#include <hip/hip_runtime.h>
#include <hip/hip_bf16.h>
#include <cmath>

// Problem constants: B=64, N=256, IN=128, E=256, H=8, F=1024
#define BB 64
#define NNODES 256
#define INF_ 128
#define EE 256
#define HH 8
#define FFN 1024
#define BNROWS 16384   // B*N

typedef __attribute__((ext_vector_type(8))) short short8;
typedef __attribute__((ext_vector_type(4))) float floatx4;
typedef __attribute__((ext_vector_type(4))) unsigned short ushort4v;

__device__ __forceinline__ float b2f(unsigned short u) {
  union { unsigned u32; float f; } w; w.u32 = ((unsigned)u) << 16; return w.f;
}
__device__ __forceinline__ unsigned short f2b(float f) {
  union { float f; unsigned u32; } w; w.f = f;
  unsigned r = w.u32 + 0x7FFFu + ((w.u32 >> 16) & 1u);   // RNE
  return (unsigned short)(r >> 16);
}
// tanh-gelu (max abs dev from exact erf-gelu ~3e-4, far below bf16 rounding)
__device__ __forceinline__ float gelu_f(float x) {
  const float z = 0.7978845608028654f * (x + 0.044715f * x * x * x);
  const float e = __expf(2.0f * z);              // v_exp_f32
  const float th = (e - 1.0f) / (e + 1.0f);
  return 0.5f * x * (1.0f + th);
}

typedef const __attribute__((address_space(1))) void GV;
typedef __attribute__((address_space(3))) void LV;

// async global->LDS: per-lane 16B source, wave-uniform LDS base (+lane*16)
__device__ __forceinline__ void gl_lds16(const unsigned short* g,
                                         unsigned short* l, int lane) {
#if __has_builtin(__builtin_amdgcn_global_load_lds)
  __builtin_amdgcn_global_load_lds((GV*)g, (LV*)l, 16, 0, 0);
#else
  *(short8*)(l + lane * 8) = *(const short8*)g;
#endif
}

// ---------------------------------------------------------------------------
// f32 -> bf16 conversion (contiguous)
// ---------------------------------------------------------------------------
__global__ void cvt_kernel(const float* __restrict__ src,
                           unsigned short* __restrict__ dst, int n)
{
  const int i = (blockIdx.x * 256 + threadIdx.x) * 4;
  if (i >= n) return;
  floatx4 v = *(const floatx4*)(src + i);
  ushort4v o;
  #pragma unroll
  for (int j = 0; j < 4; j++) o[j] = f2b(v[j]);
  *(ushort4v*)(dst + i) = o;
}

// ---------------------------------------------------------------------------
// Tiled transpose + f32->bf16: dst[c][r] = bf16(src[r][c]); src (R x C).
// slot >= 0 remaps output row c -> (c>>9)*1536 + slot*512 + (c&511)  (QKV pack)
// grid (C/32, R/32), block (32,8)
// ---------------------------------------------------------------------------
__global__ void tcvt_kernel(const float* __restrict__ src,
                            unsigned short* __restrict__ dst,
                            int R, int C, int slot)
{
  __shared__ float tile[32][33];
  const int c0 = blockIdx.x * 32, r0 = blockIdx.y * 32;
  const int tx = threadIdx.x, ty = threadIdx.y;
  #pragma unroll
  for (int i = ty; i < 32; i += 8)
    tile[i][tx] = src[(long long)(r0 + i) * C + c0 + tx];
  __syncthreads();
  #pragma unroll
  for (int i = ty; i < 32; i += 8) {
    const int c = c0 + i;
    const int dr = (slot < 0) ? c : ((c >> 9) * 1536 + slot * 512 + (c & 511));
    dst[(long long)dr * R + r0 + tx] = f2b(tile[tx][i]);
  }
}

// ---------------------------------------------------------------------------
// Batched bf16 MFMA GEMM, tile 128x128, BK=128 chunks, 512 threads (8 waves,
// 2x4), each wave 64x32 (acc[4][2]). A (M,K) rm; B (N,K) rm (always NT).
// LDS: 128 rows x 16 slots of 16B per matrix (32KB each); slot s holds
// k-octet q = s ^ (r&7)  (XOR swizzle: DMA-contiguous AND conflict-free).
// Staging: 32 DMAs/matrix/chunk; DMA d stages rows 4d..4d+3 (1KB contig LDS);
// lane: sub=lane>>4 -> row 4d+sub, q=lane&15 -> global col octet q^(row&7).
// modes:
//  0: f32 store | 1: bf16 store | 2: f32 accumulate | 3: bf16 gelu(val+aux1[col])
//  5: TT store: b=row>>8,n=row&255 -> bf16 C[b*65536+col*256+n]
//  7: scores: bf16 C[..] = val*0.0625 + aux1[zb*65536+row*256+col]
//  8: final:  f32 C[row*256+col] = gcn[i]+attf[i]+(val+aux1[col])*mask[row]
//  9: GCN epi (C'=U^T): token=zb*256+col, feat=row; g=relu((val+aux1[feat])*mask[token]);
//     bf16 C[token*256+feat]=g; gcn[...] (flag? += : =) g
// 11: QKV split: col<1024 -> bf16 C; else V^T -> aux2[z2*65536+(col&255)*256+(row&255)]
// ---------------------------------------------------------------------------
__launch_bounds__(512, 4)
__global__ void gemm_kernel(const unsigned short* __restrict__ A, int lda,
                            long long sAo, long long sAi,
                            const unsigned short* __restrict__ Bm, int ldb,
                            long long sBo, long long sBi,
                            void* __restrict__ Cv, int ldc,
                            long long sCo, long long sCi,
                            int K, int zshift, int mode, int flag,
                            const float* __restrict__ aux1,
                            const float* __restrict__ mask,
                            float* __restrict__ gcn,
                            void* __restrict__ aux2)
{
  __shared__ __align__(16) unsigned short sA[16384];   // 32KB
  __shared__ __align__(16) unsigned short sB[16384];   // 32KB

  const int t = threadIdx.x;
  const int z = blockIdx.z;
  const int zi = z & ((1 << zshift) - 1);
  const int zb = z >> zshift;
  const int m0 = blockIdx.x * 128;
  const int n0 = blockIdx.y * 128;
  A  += zb * sAo + zi * sAi;
  Bm += zb * sBo + zi * sBi;
  const long long cbase = zb * sCo + zi * sCi;

  const int lane = t & 63;
  const int w = t >> 6;              // wave 0..7
  const int wm = w >> 2, wn = w & 3; // 2 x 4
  const int lm = lane & 15, qd = lane >> 4;

  floatx4 acc[4][2] = {};

  // ---- DMA source pointers: this wave's 4 row-groups per matrix ----
  const int sub = lane >> 4;        // 0..3
  const int qs  = lane & 15;        // slot within row
  const unsigned short* pA[4];
  const unsigned short* pB[4];
  #pragma unroll
  for (int i = 0; i < 4; i++) {
    const int d = w * 4 + i;        // DMA index 0..31
    const int r = d * 4 + sub;      // tile row 0..127
    const int co = (qs ^ (r & 7)) * 8;   // swizzled col octet (elements)
    pA[i] = A + (long long)(m0 + r) * lda + co;
    pB[i] = Bm + (long long)(n0 + r) * ldb + co;
  }

  for (int kk = 0; kk < K; kk += 128) {
    #pragma unroll
    for (int i = 0; i < 4; i++) {
      gl_lds16(pA[i] + kk, &sA[(w * 4 + i) * 512], lane);
      gl_lds16(pB[i] + kk, &sB[(w * 4 + i) * 512], lane);
    }
    __syncthreads();

    #pragma unroll
    for (int ks = 0; ks < 4; ks++) {
      short8 af[4], bg[2];
      const int q = ks * 4 + qd;          // k-octet 0..15
      #pragma unroll
      for (int mi = 0; mi < 4; mi++) {
        const int r = wm * 64 + mi * 16 + lm;
        af[mi] = *(const short8*)&sA[r * 128 + ((q ^ (r & 7)) * 8)];
      }
      #pragma unroll
      for (int ni = 0; ni < 2; ni++) {
        const int r = wn * 32 + ni * 16 + lm;
        bg[ni] = *(const short8*)&sB[r * 128 + ((q ^ (r & 7)) * 8)];
      }
      #pragma unroll
      for (int mi = 0; mi < 4; mi++)
        #pragma unroll
        for (int ni = 0; ni < 2; ni++)
          acc[mi][ni] = __builtin_amdgcn_mfma_f32_16x16x32_bf16(
              af[mi], bg[ni], acc[mi][ni], 0, 0, 0);
    }
    __syncthreads();
  }

  // ---- epilogue ----
  #pragma unroll
  for (int mi = 0; mi < 4; mi++) {
    const int row0 = m0 + wm * 64 + mi * 16 + qd * 4;
    #pragma unroll
    for (int ni = 0; ni < 2; ni++) {
      const int col = n0 + wn * 32 + ni * 16 + lm;
      floatx4 a = acc[mi][ni];
      if (mode == 0) {
        float* Cf = (float*)Cv;
        #pragma unroll
        for (int r = 0; r < 4; r++)
          Cf[cbase + (long long)(row0 + r) * ldc + col] = a[r];
      } else if (mode == 1) {
        unsigned short* Cb = (unsigned short*)Cv;
        #pragma unroll
        for (int r = 0; r < 4; r++)
          Cb[cbase + (long long)(row0 + r) * ldc + col] = f2b(a[r]);
      } else if (mode == 2) {
        float* Cf = (float*)Cv;
        #pragma unroll
        for (int r = 0; r < 4; r++)
          Cf[cbase + (long long)(row0 + r) * ldc + col] += a[r];
      } else if (mode == 3) {
        unsigned short* Cb = (unsigned short*)Cv;
        const float bv = aux1[col];
        #pragma unroll
        for (int r = 0; r < 4; r++)
          Cb[cbase + (long long)(row0 + r) * ldc + col] = f2b(gelu_f(a[r] + bv));
      } else if (mode == 5) {
        const int b = row0 >> 8, n = row0 & 255;
        ushort4v o;
        #pragma unroll
        for (int r = 0; r < 4; r++) o[r] = f2b(a[r]);
        *(ushort4v*)((unsigned short*)Cv + (long long)b * 65536 + col * 256 + n) = o;
      } else if (mode == 7) {
        unsigned short* Cb = (unsigned short*)Cv;
        #pragma unroll
        for (int r = 0; r < 4; r++) {
          const float d = aux1[(long long)zb * 65536 + (row0 + r) * 256 + col];
          Cb[cbase + (long long)(row0 + r) * ldc + col] = f2b(a[r] * 0.0625f + d);
        }
      } else if (mode == 8) {
        float* Cf = (float*)Cv;
        const float* attf = (const float*)aux2;
        const float bv = aux1[col];
        #pragma unroll
        for (int r = 0; r < 4; r++) {
          const long long idx = (long long)(row0 + r) * 256 + col;
          Cf[idx] = gcn[idx] + attf[idx] + (a[r] + bv) * mask[row0 + r];
        }
      } else if (mode == 9) {
        const int token = zb * 256 + col;
        const float m = mask[token];
        ushort4v o; floatx4 g;
        #pragma unroll
        for (int r = 0; r < 4; r++) {
          const float v = fmaxf((a[r] + aux1[row0 + r]) * m, 0.f);
          o[r] = f2b(v); g[r] = v;
        }
        *(ushort4v*)((unsigned short*)Cv + (long long)token * 256 + row0) = o;
        float* gp = gcn + (long long)token * 256 + row0;
        if (flag) { floatx4 old = *(const floatx4*)gp; g += old; }
        *(floatx4*)gp = g;
      } else { // 11
        if (n0 < 1024) {
          unsigned short* Cb = (unsigned short*)Cv;
          #pragma unroll
          for (int r = 0; r < 4; r++)
            Cb[cbase + (long long)(row0 + r) * ldc + col] = f2b(a[r]);
        } else {
          const int z2 = (row0 >> 8) * 2 + ((col - 1024) >> 8);
          const int e = col & 255, n = row0 & 255;
          ushort4v o;
          #pragma unroll
          for (int r = 0; r < 4; r++) o[r] = f2b(a[r]);
          *(ushort4v*)((unsigned short*)aux2 + (long long)z2 * 65536 + e * 256 + n) = o;
        }
      }
    }
  }
}

// ---------------------------------------------------------------------------
// dis = rsqrt(clip(rowsum(A),1,inf)); A = adj (f32) with diag forced to 1
// ---------------------------------------------------------------------------
__global__ void deg_kernel(const float* __restrict__ adj,
                           float* __restrict__ dis)
{
  const int g = blockIdx.x * 4 + (threadIdx.x >> 6);
  const int lane = threadIdx.x & 63;
  const int i = g & 255;
  floatx4 v = *(const floatx4*)(adj + (long long)g * 256 + lane * 4);
  float s = 0.f;
  #pragma unroll
  for (int jj = 0; jj < 4; jj++) {
    const int j = lane * 4 + jj;
    s += (j == i) ? 1.0f : v[jj];
  }
  #pragma unroll
  for (int off = 32; off > 0; off >>= 1) s += __shfl_xor(s, off);
  if (lane == 0) dis[g] = 1.0f / sqrtf(fmaxf(s, 1.0f));
}

// An[b,i,j] = bf16(dis_i * A_ij * dis_j)  (exactly symmetric)
__global__ void an_kernel(const float* __restrict__ adj,
                          const float* __restrict__ dis,
                          unsigned short* __restrict__ An)
{
  const long long base = ((long long)blockIdx.x * 256 + threadIdx.x) * 4;
  const int rowg = (int)(base >> 8);
  const int i = rowg & 255;
  const int brow = rowg & ~255;
  const int j0 = (int)(base & 255);
  const float di = dis[rowg];
  floatx4 v = *(const floatx4*)(adj + base);
  ushort4v o;
  #pragma unroll
  for (int jj = 0; jj < 4; jj++) {
    const int j = j0 + jj;
    const float a = (j == i) ? 1.0f : v[jj];
    o[jj] = f2b(di * dis[brow + j] * a);
  }
  *(ushort4v*)(An + base) = o;
}

// LayerNorm over last dim (256): out_bf16 = (x-mean)*rsqrt(var+1e-5)*g + b
__global__ void ln_kernel(const float* __restrict__ X,
                          const float* __restrict__ gam,
                          const float* __restrict__ bet,
                          unsigned short* __restrict__ out)
{
  const int g = blockIdx.x * 4 + (threadIdx.x >> 6);
  const int lane = threadIdx.x & 63;
  floatx4 v = *(const floatx4*)(X + (long long)g * 256 + lane * 4);
  float s = v[0] + v[1] + v[2] + v[3];
  float sq = v[0]*v[0] + v[1]*v[1] + v[2]*v[2] + v[3]*v[3];
  #pragma unroll
  for (int off = 32; off > 0; off >>= 1) {
    s  += __shfl_xor(s, off);
    sq += __shfl_xor(sq, off);
  }
  const float mean = s * (1.0f / 256.0f);
  const float var = sq * (1.0f / 256.0f) - mean * mean;
  const float rs = 1.0f / sqrtf(var + 1e-5f);
  ushort4v o;
  #pragma unroll
  for (int jj = 0; jj < 4; jj++) {
    const int c = lane * 4 + jj;
    o[jj] = f2b((v[jj] - mean) * rs * gam[c] + bet[c]);
  }
  *(ushort4v*)(out + (long long)g * 256 + lane * 4) = o;
}

// in-place masked softmax on bf16 scores; row g = z*256+i, z=(b*2+h')
__global__ void softmax_kernel(unsigned short* __restrict__ S,
                               const float* __restrict__ mask)
{
  const int g = blockIdx.x * 4 + (threadIdx.x >> 6);
  const int lane = threadIdx.x & 63;
  const int b = g >> 9;
  const int i = g & 255;
  const float mi = mask[b * 256 + i];
  const long long base = (long long)g * 256 + lane * 4;
  ushort4v s4 = *(const ushort4v*)(S + base);
  float val[4]; bool vld[4];
  #pragma unroll
  for (int jj = 0; jj < 4; jj++) {
    const int j = lane * 4 + jj;
    const float mj = mask[b * 256 + j];
    vld[jj] = (mi != 0.f) && (mj != 0.f);
    val[jj] = vld[jj] ? b2f(s4[jj]) : -1e9f;
  }
  float mx = fmaxf(fmaxf(val[0], val[1]), fmaxf(val[2], val[3]));
  #pragma unroll
  for (int off = 32; off > 0; off >>= 1) mx = fmaxf(mx, __shfl_xor(mx, off));
  float es[4]; float sum = 0.f;
  #pragma unroll
  for (int jj = 0; jj < 4; jj++) { es[jj] = __expf(val[jj] - mx); sum += es[jj]; }
  #pragma unroll
  for (int off = 32; off > 0; off >>= 1) sum += __shfl_xor(sum, off);
  const float inv = 1.0f / sum;
  ushort4v o;
  #pragma unroll
  for (int jj = 0; jj < 4; jj++)
    o[jj] = vld[jj] ? f2b(es[jj] * inv) : (unsigned short)0;
  *(ushort4v*)(S + base) = o;
}

// in-place: U = GCN + (U + bo[col]) * mask[row]
__global__ void att_epi_kernel(float* U,
                               const float* __restrict__ bo,
                               const float* __restrict__ mask,
                               const float* __restrict__ GCN)
{
  const long long base = ((long long)blockIdx.x * 256 + threadIdx.x) * 4;
  const int col = (int)(base & 255);
  const int row = (int)(base >> 8);
  const float m = mask[row];
  floatx4 o = *(const floatx4*)(U + base);
  floatx4 g = *(const floatx4*)(GCN + base);
  floatx4 r;
  #pragma unroll
  for (int jj = 0; jj < 4; jj++) r[jj] = g[jj] + (o[jj] + bo[col + jj]) * m;
  *(floatx4*)(U + base) = r;
}

// ---------------------------------------------------------------------------
static inline void launch_gemm(hipStream_t st, int M, int N, int batch,
    const void* A, int lda, long long sAo, long long sAi,
    const void* B, int ldb, long long sBo, long long sBi,
    void* C, int ldc, long long sCo, long long sCi,
    int K, int zshift, int mode, int flag,
    const float* aux1, const float* mask, float* gcn, void* aux2)
{
  dim3 grid(M / 128, N / 128, batch), blk(512);
  gemm_kernel<<<grid, blk, 0, st>>>(
      (const unsigned short*)A, lda, sAo, sAi,
      (const unsigned short*)B, ldb, sBo, sBi,
      C, ldc, sCo, sCi, K, zshift, mode, flag, aux1, mask, gcn, aux2);
}

extern "C" void kernel_launch(void* const* d_in, const int* in_sizes, int n_in,
                              void* d_out, int out_size, void* d_ws, size_t ws_size,
                              hipStream_t stream)
{
  (void)in_sizes; (void)n_in; (void)out_size;
  const float* x    = (const float*)d_in[0];
  const float* adj  = (const float*)d_in[1];
  const float* mask = (const float*)d_in[2];
  const float* dist = (const float*)d_in[3];
  const float* W1   = (const float*)d_in[4];
  const float* b1   = (const float*)d_in[5];
  const float* W2   = (const float*)d_in[6];
  const float* b2   = (const float*)d_in[7];
  const float* W3   = (const float*)d_in[8];
  const float* b3   = (const float*)d_in[9];
  const float* ln1g = (const float*)d_in[10];
  const float* ln1b = (const float*)d_in[11];
  const float* Wq   = (const float*)d_in[12];
  const float* Wk   = (const float*)d_in[13];
  const float* Wv   = (const float*)d_in[14];
  const float* Wo   = (const float*)d_in[15];
  const float* bo   = (const float*)d_in[16];
  const float* ln2g = (const float*)d_in[17];
  const float* ln2b = (const float*)d_in[18];
  const float* Wf1  = (const float*)d_in[19];
  const float* bf1  = (const float*)d_in[20];
  const float* Wf2  = (const float*)d_in[21];
  const float* bf2  = (const float*)d_in[22];

  char* w = (char*)d_ws;
  auto alloc = [&](size_t sz) { void* p = (void*)w; w += sz; return p; };
  // persistent
  unsigned short* W1T   = (unsigned short*)alloc(65536);      // (256,128)
  unsigned short* W2T   = (unsigned short*)alloc(131072);     // (256,256)
  unsigned short* W3T   = (unsigned short*)alloc(131072);
  unsigned short* WQKVT = (unsigned short*)alloc(3145728);    // (6144,256) grouped
  unsigned short* WOT   = (unsigned short*)alloc(1048576);    // (256,2048)
  unsigned short* WF1T  = (unsigned short*)alloc(524288);     // (1024,256)
  unsigned short* WF2T  = (unsigned short*)alloc(524288);     // (256,1024)
  unsigned short* XBF   = (unsigned short*)alloc(4194304);    // (16384,128)
  float*          GCN   = (float*)         alloc(16777216);   // (16384,256) f32
  float*          U     = (float*)         alloc(16777216);   // O accum / ATT
  unsigned short* HBF   = (unsigned short*)alloc(8388608);    // (16384,256) bf16
  float*          DIS   = (float*)         alloc(65536);
  // scratch union (max phase = attention, 100.7 MB)
  char* scratch = (char*)alloc(100663296);
  if ((size_t)(w - (char*)d_ws) > ws_size) return;
  // gcn phase views
  unsigned short* AN  = (unsigned short*)scratch;              // 8.4 MB
  unsigned short* TT  = (unsigned short*)(scratch + 8388608);  // 8.4 MB
  unsigned short* GBF = (unsigned short*)(scratch + 16777216); // 8.4 MB
  // attention phase views
  unsigned short* QKVG = (unsigned short*)scratch;                 // 50.3 MB
  unsigned short* VT   = (unsigned short*)(scratch + 50331648);    // 16.8 MB
  unsigned short* S    = (unsigned short*)(scratch + 67108864);    // 16.8 MB
  unsigned short* YG   = (unsigned short*)(scratch + 83886080);    // 16.8 MB
  // ffn phase view
  unsigned short* FFB  = (unsigned short*)scratch;                 // 33.6 MB

  // ---- weight packing (transpose + cvt) ----
  dim3 tb(32, 8);
  tcvt_kernel<<<dim3(8, 4),  tb, 0, stream>>>(W1,  W1T,  128,  256, -1);
  tcvt_kernel<<<dim3(8, 8),  tb, 0, stream>>>(W2,  W2T,  256,  256, -1);
  tcvt_kernel<<<dim3(8, 8),  tb, 0, stream>>>(W3,  W3T,  256,  256, -1);
  tcvt_kernel<<<dim3(64, 8), tb, 0, stream>>>(Wq,  WQKVT, 256, 2048, 0);
  tcvt_kernel<<<dim3(64, 8), tb, 0, stream>>>(Wk,  WQKVT, 256, 2048, 1);
  tcvt_kernel<<<dim3(64, 8), tb, 0, stream>>>(Wv,  WQKVT, 256, 2048, 2);
  tcvt_kernel<<<dim3(8, 64), tb, 0, stream>>>(Wo,  WOT,  2048,  256, -1);
  tcvt_kernel<<<dim3(32, 8), tb, 0, stream>>>(Wf1, WF1T,  256, 1024, -1);
  tcvt_kernel<<<dim3(8, 32), tb, 0, stream>>>(Wf2, WF2T, 1024,  256, -1);
  cvt_kernel<<<2048, 256, 0, stream>>>(x, XBF, BNROWS * INF_);

  // ---- adjacency normalization ----
  deg_kernel<<<4096, 256, 0, stream>>>(adj, DIS);
  an_kernel<<<4096, 256, 0, stream>>>(adj, DIS, AN);

  // ---- GCN stack: W-GEMM stores T^T (mode 5); An-GEMM (B=An, symmetric)
  //      computes U^T with fused bias+mask+relu+GCN-accum epilogue (mode 9)
  launch_gemm(stream, BNROWS, EE, 1, XBF, 128, 0,0, W1T, 128, 0,0,
              TT, 256, 0,0, 128, 0, 5, 0, nullptr, nullptr, nullptr, nullptr);
  launch_gemm(stream, 256, 256, BB, TT, 256, 65536,0, AN, 256, 65536,0,
              GBF, 256, 0,0, 256, 0, 9, 0, b1, mask, GCN, nullptr);
  launch_gemm(stream, BNROWS, EE, 1, GBF, 256, 0,0, W2T, 256, 0,0,
              TT, 256, 0,0, 256, 0, 5, 0, nullptr, nullptr, nullptr, nullptr);
  launch_gemm(stream, 256, 256, BB, TT, 256, 65536,0, AN, 256, 65536,0,
              GBF, 256, 0,0, 256, 0, 9, 1, b2, mask, GCN, nullptr);
  launch_gemm(stream, BNROWS, EE, 1, GBF, 256, 0,0, W3T, 256, 0,0,
              TT, 256, 0,0, 256, 0, 5, 0, nullptr, nullptr, nullptr, nullptr);
  launch_gemm(stream, 256, 256, BB, TT, 256, 65536,0, AN, 256, 65536,0,
              GBF, 256, 0,0, 256, 0, 9, 1, b3, mask, GCN, nullptr);

  // ---- LN1 ----
  ln_kernel<<<4096, 256, 0, stream>>>(GCN, ln1g, ln1b, HBF);

  // ---- attention: 4 groups of 2 heads ----
  for (int g = 0; g < 4; g++) {
    // QKV for 2 heads: C cols 0-511 q, 512-1023 k; v stored transposed to VT
    launch_gemm(stream, BNROWS, 1536, 1, HBF, 256, 0,0,
                WQKVT + (long long)g * 1536 * 256, 256, 0,0,
                QKVG, 1536, 0,0, 256, 0, 11, 0, nullptr, nullptr, nullptr, VT);
    // scores (z = b*2+h'): bf16 S = qk*0.0625 + dist  (mask applied in softmax)
    launch_gemm(stream, 256, 256, 128, QKVG, 1536, 393216, 256,
                QKVG + 512, 1536, 393216, 256,
                S, 256, 131072, 65536, 256, 1, 7, 0, dist, nullptr, nullptr, nullptr);
    softmax_kernel<<<8192, 256, 0, stream>>>(S, mask);
    // y = P v   (B = V^T, NT)
    launch_gemm(stream, 256, 256, 128, S, 256, 131072, 65536,
                VT, 256, 131072, 65536,
                YG, 512, 131072, 256, 256, 1, 1, 0, nullptr, nullptr, nullptr, nullptr);
    // O (+)= Y_g @ Wo_g
    launch_gemm(stream, BNROWS, EE, 1, YG, 512, 0,0,
                WOT + g * 512, 2048, 0,0,
                U, 256, 0,0, 512, 0, (g == 0 ? 0 : 2), 0,
                nullptr, nullptr, nullptr, nullptr);
  }

  // ---- residual + LN2 + FFN (final residual fused into FFN2 epilogue) ----
  att_epi_kernel<<<4096, 256, 0, stream>>>(U, bo, mask, GCN);
  ln_kernel<<<4096, 256, 0, stream>>>(U, ln2g, ln2b, HBF);
  launch_gemm(stream, BNROWS, FFN, 1, HBF, 256, 0,0, WF1T, 256, 0,0,
              FFB, 1024, 0,0, 256, 0, 3, 0, bf1, nullptr, nullptr, nullptr);
  launch_gemm(stream, BNROWS, EE, 1, FFB, 1024, 0,0, WF2T, 1024, 0,0,
              d_out, 256, 0,0, 1024, 0, 8, 0, bf2, mask, GCN, U);
}

// Round 5
// 532.306 us; speedup vs baseline: 1.7677x; 1.2468x over previous
//
#include <hip/hip_runtime.h>
#include <hip/hip_bf16.h>
#include <cmath>

// Problem constants: B=64, N=256, IN=128, E=256, H=8, F=1024
#define BB 64
#define NNODES 256
#define INF_ 128
#define EE 256
#define HH 8
#define FFN 1024
#define BNROWS 16384   // B*N

typedef __attribute__((ext_vector_type(8))) short short8;
typedef __attribute__((ext_vector_type(4))) float floatx4;
typedef __attribute__((ext_vector_type(4))) unsigned short ushort4v;

__device__ __forceinline__ float b2f(unsigned short u) {
  union { unsigned u32; float f; } w; w.u32 = ((unsigned)u) << 16; return w.f;
}
__device__ __forceinline__ unsigned short f2b(float f) {
  union { float f; unsigned u32; } w; w.f = f;
  unsigned r = w.u32 + 0x7FFFu + ((w.u32 >> 16) & 1u);   // RNE
  return (unsigned short)(r >> 16);
}
// tanh-gelu (max abs dev from exact erf-gelu ~3e-4, far below bf16 rounding)
__device__ __forceinline__ float gelu_f(float x) {
  const float z = 0.7978845608028654f * (x + 0.044715f * x * x * x);
  const float e = __expf(2.0f * z);
  const float th = (e - 1.0f) / (e + 1.0f);
  return 0.5f * x * (1.0f + th);
}

typedef const __attribute__((address_space(1))) void GV;
typedef __attribute__((address_space(3))) void LV;

// async global->LDS: per-lane 16B source, wave-uniform LDS base (+lane*16)
__device__ __forceinline__ void gl_lds16(const unsigned short* g,
                                         unsigned short* l, int lane) {
#if __has_builtin(__builtin_amdgcn_global_load_lds)
  __builtin_amdgcn_global_load_lds((GV*)g, (LV*)l, 16, 0, 0);
#else
  *(short8*)(l + lane * 8) = *(const short8*)g;
#endif
}

// ---------------------------------------------------------------------------
// f32 -> bf16 conversion (contiguous)
// ---------------------------------------------------------------------------
__global__ void cvt_kernel(const float* __restrict__ src,
                           unsigned short* __restrict__ dst, int n)
{
  const int i = (blockIdx.x * 256 + threadIdx.x) * 4;
  if (i >= n) return;
  floatx4 v = *(const floatx4*)(src + i);
  ushort4v o;
  #pragma unroll
  for (int j = 0; j < 4; j++) o[j] = f2b(v[j]);
  *(ushort4v*)(dst + i) = o;
}

// ---------------------------------------------------------------------------
// Tiled transpose + f32->bf16: dst[c][r] = bf16(src[r][c]); src (R x C).
// grid (C/32, R/32), block (32,8)
// ---------------------------------------------------------------------------
__global__ void tcvt_kernel(const float* __restrict__ src,
                            unsigned short* __restrict__ dst,
                            int R, int C)
{
  __shared__ float tile[32][33];
  const int c0 = blockIdx.x * 32, r0 = blockIdx.y * 32;
  const int tx = threadIdx.x, ty = threadIdx.y;
  #pragma unroll
  for (int i = ty; i < 32; i += 8)
    tile[i][tx] = src[(long long)(r0 + i) * C + c0 + tx];
  __syncthreads();
  #pragma unroll
  for (int i = ty; i < 32; i += 8)
    dst[(long long)(c0 + i) * R + r0 + tx] = f2b(tile[tx][i]);
}

// ---------------------------------------------------------------------------
// Batched bf16 MFMA GEMM, tile 128x128, BK=128 chunks, 512 threads (8 waves,
// 2x4), each wave 64x32 (acc[4][2]). A (M,K) rm; B (N,K) rm (always NT).
// LDS rows x 16 slots of 16B; slot s holds k-octet q = s ^ (r&7) (XOR swizzle).
// modes:
//  0: f32 store | 1: bf16 store | 2: f32 accumulate | 3: bf16 gelu(val+aux1[col])
//  5: TT store: b=row>>8,n=row&255 -> bf16 C[b*65536+col*256+n]
//  8: final:  f32 C[row*256+col] = gcn[i]+attf[i]+(val+aux1[col])*mask[row]
//  9: GCN epi (C'=U^T): token=zb*256+col, feat=row; g=relu((val+aux1[feat])*mask[token]);
//     bf16 C[token*256+feat]=g; gcn[...] (flag? += : =) g
// 11: QKV: col<2048 -> bf16 C[row*4096+col] = val*0.0625 (Q, pre-scaled);
//     col<4096 -> bf16 C[row*4096+col] (K);
//     else V^T -> aux2[((row>>8)*8+((col-4096)>>8))*65536 + (col&255)*256 + (row&255)]
// 12: f32 C[row*256+col] = gcn[idx] + (val + aux1[col]) * mask[row]
// ---------------------------------------------------------------------------
__launch_bounds__(512, 4)
__global__ void gemm_kernel(const unsigned short* __restrict__ A, int lda,
                            long long sAo, long long sAi,
                            const unsigned short* __restrict__ Bm, int ldb,
                            long long sBo, long long sBi,
                            void* __restrict__ Cv, int ldc,
                            long long sCo, long long sCi,
                            int K, int zshift, int mode, int flag,
                            const float* __restrict__ aux1,
                            const float* __restrict__ mask,
                            float* __restrict__ gcn,
                            void* __restrict__ aux2)
{
  __shared__ __align__(16) unsigned short sA[16384];   // 32KB
  __shared__ __align__(16) unsigned short sB[16384];   // 32KB

  const int t = threadIdx.x;
  const int z = blockIdx.z;
  const int zi = z & ((1 << zshift) - 1);
  const int zb = z >> zshift;
  const int m0 = blockIdx.x * 128;
  const int n0 = blockIdx.y * 128;
  A  += zb * sAo + zi * sAi;
  Bm += zb * sBo + zi * sBi;
  const long long cbase = zb * sCo + zi * sCi;

  const int lane = t & 63;
  const int w = t >> 6;              // wave 0..7
  const int wm = w >> 2, wn = w & 3; // 2 x 4
  const int lm = lane & 15, qd = lane >> 4;

  floatx4 acc[4][2] = {};

  const int sub = lane >> 4;        // 0..3
  const int qs  = lane & 15;        // slot within row
  const unsigned short* pA[4];
  const unsigned short* pB[4];
  #pragma unroll
  for (int i = 0; i < 4; i++) {
    const int d = w * 4 + i;        // DMA index 0..31
    const int r = d * 4 + sub;      // tile row 0..127
    const int co = (qs ^ (r & 7)) * 8;   // swizzled col octet (elements)
    pA[i] = A + (long long)(m0 + r) * lda + co;
    pB[i] = Bm + (long long)(n0 + r) * ldb + co;
  }

  for (int kk = 0; kk < K; kk += 128) {
    #pragma unroll
    for (int i = 0; i < 4; i++) {
      gl_lds16(pA[i] + kk, &sA[(w * 4 + i) * 512], lane);
      gl_lds16(pB[i] + kk, &sB[(w * 4 + i) * 512], lane);
    }
    __syncthreads();

    #pragma unroll
    for (int ks = 0; ks < 4; ks++) {
      short8 af[4], bg[2];
      const int q = ks * 4 + qd;          // k-octet 0..15
      #pragma unroll
      for (int mi = 0; mi < 4; mi++) {
        const int r = wm * 64 + mi * 16 + lm;
        af[mi] = *(const short8*)&sA[r * 128 + ((q ^ (r & 7)) * 8)];
      }
      #pragma unroll
      for (int ni = 0; ni < 2; ni++) {
        const int r = wn * 32 + ni * 16 + lm;
        bg[ni] = *(const short8*)&sB[r * 128 + ((q ^ (r & 7)) * 8)];
      }
      #pragma unroll
      for (int mi = 0; mi < 4; mi++)
        #pragma unroll
        for (int ni = 0; ni < 2; ni++)
          acc[mi][ni] = __builtin_amdgcn_mfma_f32_16x16x32_bf16(
              af[mi], bg[ni], acc[mi][ni], 0, 0, 0);
    }
    __syncthreads();
  }

  // ---- epilogue ----
  #pragma unroll
  for (int mi = 0; mi < 4; mi++) {
    const int row0 = m0 + wm * 64 + mi * 16 + qd * 4;
    #pragma unroll
    for (int ni = 0; ni < 2; ni++) {
      const int col = n0 + wn * 32 + ni * 16 + lm;
      floatx4 a = acc[mi][ni];
      if (mode == 0) {
        float* Cf = (float*)Cv;
        #pragma unroll
        for (int r = 0; r < 4; r++)
          Cf[cbase + (long long)(row0 + r) * ldc + col] = a[r];
      } else if (mode == 1) {
        unsigned short* Cb = (unsigned short*)Cv;
        #pragma unroll
        for (int r = 0; r < 4; r++)
          Cb[cbase + (long long)(row0 + r) * ldc + col] = f2b(a[r]);
      } else if (mode == 2) {
        float* Cf = (float*)Cv;
        #pragma unroll
        for (int r = 0; r < 4; r++)
          Cf[cbase + (long long)(row0 + r) * ldc + col] += a[r];
      } else if (mode == 3) {
        unsigned short* Cb = (unsigned short*)Cv;
        const float bv = aux1[col];
        #pragma unroll
        for (int r = 0; r < 4; r++)
          Cb[cbase + (long long)(row0 + r) * ldc + col] = f2b(gelu_f(a[r] + bv));
      } else if (mode == 5) {
        const int b = row0 >> 8, n = row0 & 255;
        ushort4v o;
        #pragma unroll
        for (int r = 0; r < 4; r++) o[r] = f2b(a[r]);
        *(ushort4v*)((unsigned short*)Cv + (long long)b * 65536 + col * 256 + n) = o;
      } else if (mode == 8) {
        float* Cf = (float*)Cv;
        const float* attf = (const float*)aux2;
        const float bv = aux1[col];
        #pragma unroll
        for (int r = 0; r < 4; r++) {
          const long long idx = (long long)(row0 + r) * 256 + col;
          Cf[idx] = gcn[idx] + attf[idx] + (a[r] + bv) * mask[row0 + r];
        }
      } else if (mode == 9) {
        const int token = zb * 256 + col;
        const float m = mask[token];
        ushort4v o; floatx4 g;
        #pragma unroll
        for (int r = 0; r < 4; r++) {
          const float v = fmaxf((a[r] + aux1[row0 + r]) * m, 0.f);
          o[r] = f2b(v); g[r] = v;
        }
        *(ushort4v*)((unsigned short*)Cv + (long long)token * 256 + row0) = o;
        float* gp = gcn + (long long)token * 256 + row0;
        if (flag) { floatx4 old = *(const floatx4*)gp; g += old; }
        *(floatx4*)gp = g;
      } else if (mode == 11) {
        if (col < 2048) {
          unsigned short* Cb = (unsigned short*)Cv;
          #pragma unroll
          for (int r = 0; r < 4; r++)
            Cb[(long long)(row0 + r) * 4096 + col] = f2b(a[r] * 0.0625f);
        } else if (col < 4096) {
          unsigned short* Cb = (unsigned short*)Cv;
          #pragma unroll
          for (int r = 0; r < 4; r++)
            Cb[(long long)(row0 + r) * 4096 + col] = f2b(a[r]);
        } else {
          const int z2 = (row0 >> 8) * 8 + ((col - 4096) >> 8);
          const int e = col & 255, n = row0 & 255;
          ushort4v o;
          #pragma unroll
          for (int r = 0; r < 4; r++) o[r] = f2b(a[r]);
          *(ushort4v*)((unsigned short*)aux2 + (long long)z2 * 65536 + e * 256 + n) = o;
        }
      } else { // 12: U = GCN + (val + bo)*mask
        float* Cf = (float*)Cv;
        const float bv = aux1[col];
        #pragma unroll
        for (int r = 0; r < 4; r++) {
          const long long idx = (long long)(row0 + r) * 256 + col;
          Cf[idx] = gcn[idx] + (a[r] + bv) * mask[row0 + r];
        }
      }
    }
  }
}

// ---------------------------------------------------------------------------
// Fused attention: per block (m-tile 128, z=b*8+h): S = Q·K^T (f32 regs, full
// N=256), += dist, mask, row softmax, P(bf16)->LDS, Y = P·V, Y overwrites Q.
// Q pre-scaled by E^-0.5. LDS: sQ 16KB (Q-chunk / P-chunk), sKV 32KB (K/V
// chunk), red 4KB. BK=64 chunks. Invalid cols: exp underflows to exactly 0;
// invalid rows are killed later by the Wo-epilogue mask.
// ---------------------------------------------------------------------------
__launch_bounds__(512, 2)
__global__ void attn_kernel(unsigned short* __restrict__ QKY,   // (16384,4096)
                            const unsigned short* __restrict__ VT, // (512,256,256)
                            const float* __restrict__ dist,
                            const float* __restrict__ mask)
{
  __shared__ __align__(16) unsigned short sQ[8192];    // 16KB
  __shared__ __align__(16) unsigned short sKV[16384];  // 32KB
  __shared__ float redm[4][128];
  __shared__ float reds[4][128];

  const int mt = blockIdx.x;         // 0..1
  const int z  = blockIdx.y;         // b*8+h
  const int b  = z >> 3, h = z & 7;
  const int t = threadIdx.x, lane = t & 63, w = t >> 6;
  const int wm = w >> 2, wn = w & 3;
  const int lm = lane & 15, qd = lane >> 4;
  const int m0 = mt * 128;

  unsigned short* Qbase = QKY + ((long long)(b * 256 + m0)) * 4096 + h * 256;
  const unsigned short* Kbase = QKY + ((long long)(b * 256)) * 4096 + 2048 + h * 256;
  const unsigned short* Vbase = VT + (long long)z * 65536;
  const float* maskb = mask + b * 256;
  const float* distb = dist + (long long)b * 65536;

  const int rin = lane >> 3;   // row within DMA (0..7)
  const int qs  = lane & 7;    // octet slot (0..7)

  floatx4 S[4][4] = {};

  // ---- QK phase: 4 chunks of BK=64 over e ----
  for (int c = 0; c < 4; c++) {
    const int e0 = c * 64;
    #pragma unroll
    for (int i = 0; i < 2; i++) {           // Q: 16 DMAs (rows 8d..8d+7)
      const int d = w * 2 + i;
      const int r = d * 8 + rin;
      gl_lds16(Qbase + (long long)r * 4096 + e0 + ((qs ^ (r & 7)) * 8),
               &sQ[d * 512], lane);
    }
    #pragma unroll
    for (int i = 0; i < 4; i++) {           // K: 32 DMAs
      const int d = w * 4 + i;
      const int r = d * 8 + rin;
      gl_lds16(Kbase + (long long)r * 4096 + e0 + ((qs ^ (r & 7)) * 8),
               &sKV[d * 512], lane);
    }
    __syncthreads();
    #pragma unroll
    for (int ks = 0; ks < 2; ks++) {
      short8 af[4], bg[4];
      const int o = ks * 4 + qd;            // k-octet 0..7
      #pragma unroll
      for (int mi = 0; mi < 4; mi++) {
        const int r = wm * 64 + mi * 16 + lm;
        af[mi] = *(const short8*)&sQ[r * 64 + ((o ^ (r & 7)) * 8)];
      }
      #pragma unroll
      for (int ni = 0; ni < 4; ni++) {
        const int r = wn * 64 + ni * 16 + lm;
        bg[ni] = *(const short8*)&sKV[r * 64 + ((o ^ (r & 7)) * 8)];
      }
      #pragma unroll
      for (int mi = 0; mi < 4; mi++)
        #pragma unroll
        for (int ni = 0; ni < 4; ni++)
          S[mi][ni] = __builtin_amdgcn_mfma_f32_16x16x32_bf16(
              af[mi], bg[ni], S[mi][ni], 0, 0, 0);
    }
    __syncthreads();
  }

  // ---- softmax over cols (keys) ----
  float mk[4];
  #pragma unroll
  for (int ni = 0; ni < 4; ni++) mk[ni] = maskb[wn * 64 + ni * 16 + lm];

  float lred[4][4];
  #pragma unroll
  for (int mi = 0; mi < 4; mi++) {
    #pragma unroll
    for (int r = 0; r < 4; r++) {
      const int row = wm * 64 + mi * 16 + qd * 4 + r;
      const float mq = maskb[m0 + row];
      float mx = -3e38f;
      #pragma unroll
      for (int ni = 0; ni < 4; ni++) {
        const int col = wn * 64 + ni * 16 + lm;
        const float dv = distb[(long long)(m0 + row) * 256 + col];
        const float v = (mq != 0.f && mk[ni] != 0.f) ? (S[mi][ni][r] + dv) : -1e9f;
        S[mi][ni][r] = v;
        mx = fmaxf(mx, v);
      }
      lred[mi][r] = mx;
    }
  }
  #pragma unroll
  for (int off = 1; off < 16; off <<= 1)
    #pragma unroll
    for (int mi = 0; mi < 4; mi++)
      #pragma unroll
      for (int r = 0; r < 4; r++)
        lred[mi][r] = fmaxf(lred[mi][r], __shfl_xor(lred[mi][r], off));
  if (lm == 0)
    #pragma unroll
    for (int mi = 0; mi < 4; mi++)
      #pragma unroll
      for (int r = 0; r < 4; r++)
        redm[wn][wm * 64 + mi * 16 + qd * 4 + r] = lred[mi][r];
  __syncthreads();

  #pragma unroll
  for (int mi = 0; mi < 4; mi++) {
    #pragma unroll
    for (int r = 0; r < 4; r++) {
      const int row = wm * 64 + mi * 16 + qd * 4 + r;
      const float gmax = fmaxf(fmaxf(redm[0][row], redm[1][row]),
                               fmaxf(redm[2][row], redm[3][row]));
      float s = 0.f;
      #pragma unroll
      for (int ni = 0; ni < 4; ni++) {
        const float e = __expf(S[mi][ni][r] - gmax);   // invalid -> exactly 0
        S[mi][ni][r] = e;
        s += e;
      }
      lred[mi][r] = s;
    }
  }
  #pragma unroll
  for (int off = 1; off < 16; off <<= 1)
    #pragma unroll
    for (int mi = 0; mi < 4; mi++)
      #pragma unroll
      for (int r = 0; r < 4; r++)
        lred[mi][r] += __shfl_xor(lred[mi][r], off);
  if (lm == 0)
    #pragma unroll
    for (int mi = 0; mi < 4; mi++)
      #pragma unroll
      for (int r = 0; r < 4; r++)
        reds[wn][wm * 64 + mi * 16 + qd * 4 + r] = lred[mi][r];
  __syncthreads();

  #pragma unroll
  for (int mi = 0; mi < 4; mi++) {
    #pragma unroll
    for (int r = 0; r < 4; r++) {
      const int row = wm * 64 + mi * 16 + qd * 4 + r;
      const float gs = redm[0][row] * 0.f +   // keep redm live semantics simple
                       reds[0][row] + reds[1][row] + reds[2][row] + reds[3][row];
      const float inv = 1.0f / gs;            // gs >= 1 always (diagonal valid or all-invalid sum=256)
      #pragma unroll
      for (int ni = 0; ni < 4; ni++) S[mi][ni][r] *= inv;
    }
  }

  // ---- PV phase: 4 chunks of BK=64 over keys n ----
  floatx4 Y[4][4] = {};
  for (int c = 0; c < 4; c++) {
    #pragma unroll
    for (int i = 0; i < 4; i++) {           // V: 32 DMAs (rows e 8d..8d+7)
      const int d = w * 4 + i;
      const int r = d * 8 + rin;
      gl_lds16(Vbase + (long long)r * 256 + c * 64 + ((qs ^ (r & 7)) * 8),
               &sKV[d * 512], lane);
    }
    if (wn == c) {                          // write P chunk (cols c*64..c*64+63)
      #pragma unroll
      for (int mi = 0; mi < 4; mi++)
        #pragma unroll
        for (int r = 0; r < 4; r++) {
          const int row = wm * 64 + mi * 16 + qd * 4 + r;
          #pragma unroll
          for (int ni = 0; ni < 4; ni++) {
            const int kl = ni * 16 + lm;
            const int slot = (kl >> 3) ^ (row & 7);
            sQ[row * 64 + slot * 8 + (kl & 7)] = f2b(S[mi][ni][r]);
          }
        }
    }
    __syncthreads();
    #pragma unroll
    for (int ks = 0; ks < 2; ks++) {
      short8 af[4], bg[4];
      const int o = ks * 4 + qd;
      #pragma unroll
      for (int mi = 0; mi < 4; mi++) {
        const int r = wm * 64 + mi * 16 + lm;
        af[mi] = *(const short8*)&sQ[r * 64 + ((o ^ (r & 7)) * 8)];
      }
      #pragma unroll
      for (int ni = 0; ni < 4; ni++) {
        const int r = wn * 64 + ni * 16 + lm;
        bg[ni] = *(const short8*)&sKV[r * 64 + ((o ^ (r & 7)) * 8)];
      }
      #pragma unroll
      for (int mi = 0; mi < 4; mi++)
        #pragma unroll
        for (int ni = 0; ni < 4; ni++)
          Y[mi][ni] = __builtin_amdgcn_mfma_f32_16x16x32_bf16(
              af[mi], bg[ni], Y[mi][ni], 0, 0, 0);
    }
    __syncthreads();
  }

  // ---- epilogue: Y (bf16) overwrites this tile's Q cols ----
  #pragma unroll
  for (int mi = 0; mi < 4; mi++)
    #pragma unroll
    for (int ni = 0; ni < 4; ni++) {
      const int col = wn * 64 + ni * 16 + lm;
      #pragma unroll
      for (int r = 0; r < 4; r++) {
        const int row = wm * 64 + mi * 16 + qd * 4 + r;
        Qbase[(long long)row * 4096 + col] = f2b(Y[mi][ni][r]);
      }
    }
}

// ---------------------------------------------------------------------------
__global__ void deg_kernel(const float* __restrict__ adj,
                           float* __restrict__ dis)
{
  const int g = blockIdx.x * 4 + (threadIdx.x >> 6);
  const int lane = threadIdx.x & 63;
  const int i = g & 255;
  floatx4 v = *(const floatx4*)(adj + (long long)g * 256 + lane * 4);
  float s = 0.f;
  #pragma unroll
  for (int jj = 0; jj < 4; jj++) {
    const int j = lane * 4 + jj;
    s += (j == i) ? 1.0f : v[jj];
  }
  #pragma unroll
  for (int off = 32; off > 0; off >>= 1) s += __shfl_xor(s, off);
  if (lane == 0) dis[g] = 1.0f / sqrtf(fmaxf(s, 1.0f));
}

__global__ void an_kernel(const float* __restrict__ adj,
                          const float* __restrict__ dis,
                          unsigned short* __restrict__ An)
{
  const long long base = ((long long)blockIdx.x * 256 + threadIdx.x) * 4;
  const int rowg = (int)(base >> 8);
  const int i = rowg & 255;
  const int brow = rowg & ~255;
  const int j0 = (int)(base & 255);
  const float di = dis[rowg];
  floatx4 v = *(const floatx4*)(adj + base);
  ushort4v o;
  #pragma unroll
  for (int jj = 0; jj < 4; jj++) {
    const int j = j0 + jj;
    const float a = (j == i) ? 1.0f : v[jj];
    o[jj] = f2b(di * dis[brow + j] * a);
  }
  *(ushort4v*)(An + base) = o;
}

__global__ void ln_kernel(const float* __restrict__ X,
                          const float* __restrict__ gam,
                          const float* __restrict__ bet,
                          unsigned short* __restrict__ out)
{
  const int g = blockIdx.x * 4 + (threadIdx.x >> 6);
  const int lane = threadIdx.x & 63;
  floatx4 v = *(const floatx4*)(X + (long long)g * 256 + lane * 4);
  float s = v[0] + v[1] + v[2] + v[3];
  float sq = v[0]*v[0] + v[1]*v[1] + v[2]*v[2] + v[3]*v[3];
  #pragma unroll
  for (int off = 32; off > 0; off >>= 1) {
    s  += __shfl_xor(s, off);
    sq += __shfl_xor(sq, off);
  }
  const float mean = s * (1.0f / 256.0f);
  const float var = sq * (1.0f / 256.0f) - mean * mean;
  const float rs = 1.0f / sqrtf(var + 1e-5f);
  ushort4v o;
  #pragma unroll
  for (int jj = 0; jj < 4; jj++) {
    const int c = lane * 4 + jj;
    o[jj] = f2b((v[jj] - mean) * rs * gam[c] + bet[c]);
  }
  *(ushort4v*)(out + (long long)g * 256 + lane * 4) = o;
}

// ---------------------------------------------------------------------------
static inline void launch_gemm(hipStream_t st, int M, int N, int batch,
    const void* A, int lda, long long sAo, long long sAi,
    const void* B, int ldb, long long sBo, long long sBi,
    void* C, int ldc, long long sCo, long long sCi,
    int K, int zshift, int mode, int flag,
    const float* aux1, const float* mask, float* gcn, void* aux2)
{
  dim3 grid(M / 128, N / 128, batch), blk(512);
  gemm_kernel<<<grid, blk, 0, st>>>(
      (const unsigned short*)A, lda, sAo, sAi,
      (const unsigned short*)B, ldb, sBo, sBi,
      C, ldc, sCo, sCi, K, zshift, mode, flag, aux1, mask, gcn, aux2);
}

extern "C" void kernel_launch(void* const* d_in, const int* in_sizes, int n_in,
                              void* d_out, int out_size, void* d_ws, size_t ws_size,
                              hipStream_t stream)
{
  (void)in_sizes; (void)n_in; (void)out_size;
  const float* x    = (const float*)d_in[0];
  const float* adj  = (const float*)d_in[1];
  const float* mask = (const float*)d_in[2];
  const float* dist = (const float*)d_in[3];
  const float* W1   = (const float*)d_in[4];
  const float* b1   = (const float*)d_in[5];
  const float* W2   = (const float*)d_in[6];
  const float* b2   = (const float*)d_in[7];
  const float* W3   = (const float*)d_in[8];
  const float* b3   = (const float*)d_in[9];
  const float* ln1g = (const float*)d_in[10];
  const float* ln1b = (const float*)d_in[11];
  const float* Wq   = (const float*)d_in[12];
  const float* Wk   = (const float*)d_in[13];
  const float* Wv   = (const float*)d_in[14];
  const float* Wo   = (const float*)d_in[15];
  const float* bo   = (const float*)d_in[16];
  const float* ln2g = (const float*)d_in[17];
  const float* ln2b = (const float*)d_in[18];
  const float* Wf1  = (const float*)d_in[19];
  const float* bf1  = (const float*)d_in[20];
  const float* Wf2  = (const float*)d_in[21];
  const float* bf2  = (const float*)d_in[22];

  char* w = (char*)d_ws;
  auto alloc = [&](size_t sz) { void* p = (void*)w; w += sz; return p; };
  // persistent (51.8 MB)
  unsigned short* W1T   = (unsigned short*)alloc(65536);      // (256,128)
  unsigned short* W2T   = (unsigned short*)alloc(131072);     // (256,256)
  unsigned short* W3T   = (unsigned short*)alloc(131072);
  unsigned short* WQKVT = (unsigned short*)alloc(3145728);    // (6144,256) q|k|v
  unsigned short* WOT   = (unsigned short*)alloc(1048576);    // (256,2048)
  unsigned short* WF1T  = (unsigned short*)alloc(524288);     // (1024,256)
  unsigned short* WF2T  = (unsigned short*)alloc(524288);     // (256,1024)
  unsigned short* XBF   = (unsigned short*)alloc(4194304);    // (16384,128)
  float*          GCN   = (float*)         alloc(16777216);   // (16384,256)
  float*          U     = (float*)         alloc(16777216);   // ATT f32
  unsigned short* HBF   = (unsigned short*)alloc(8388608);    // (16384,256)
  float*          DIS   = (float*)         alloc(65536);
  // scratch union (peak = attention: 201.3 MB)
  char* scratch = (char*)alloc(201326592);
  if ((size_t)(w - (char*)d_ws) > ws_size) return;
  // gcn phase views
  unsigned short* AN  = (unsigned short*)scratch;              // 8.4 MB
  unsigned short* TT  = (unsigned short*)(scratch + 8388608);  // 8.4 MB
  unsigned short* GBF = (unsigned short*)(scratch + 16777216); // 8.4 MB
  // attention phase views
  unsigned short* QKY = (unsigned short*)scratch;                 // (16384,4096) 134 MB
  unsigned short* VT  = (unsigned short*)(scratch + 134217728);   // (512,256,256) 67 MB
  // ffn phase view
  unsigned short* FFB = (unsigned short*)scratch;                 // 33.6 MB

  // ---- weight packing (transpose + cvt) ----
  dim3 tb(32, 8);
  tcvt_kernel<<<dim3(8, 4),  tb, 0, stream>>>(W1,  W1T,  128,  256);
  tcvt_kernel<<<dim3(8, 8),  tb, 0, stream>>>(W2,  W2T,  256,  256);
  tcvt_kernel<<<dim3(8, 8),  tb, 0, stream>>>(W3,  W3T,  256,  256);
  tcvt_kernel<<<dim3(64, 8), tb, 0, stream>>>(Wq,  WQKVT,            256, 2048);
  tcvt_kernel<<<dim3(64, 8), tb, 0, stream>>>(Wk,  WQKVT + 2048*256, 256, 2048);
  tcvt_kernel<<<dim3(64, 8), tb, 0, stream>>>(Wv,  WQKVT + 4096*256, 256, 2048);
  tcvt_kernel<<<dim3(8, 64), tb, 0, stream>>>(Wo,  WOT,  2048,  256);
  tcvt_kernel<<<dim3(32, 8), tb, 0, stream>>>(Wf1, WF1T,  256, 1024);
  tcvt_kernel<<<dim3(8, 32), tb, 0, stream>>>(Wf2, WF2T, 1024,  256);
  cvt_kernel<<<2048, 256, 0, stream>>>(x, XBF, BNROWS * INF_);

  // ---- adjacency normalization ----
  deg_kernel<<<4096, 256, 0, stream>>>(adj, DIS);
  an_kernel<<<4096, 256, 0, stream>>>(adj, DIS, AN);

  // ---- GCN stack ----
  launch_gemm(stream, BNROWS, EE, 1, XBF, 128, 0,0, W1T, 128, 0,0,
              TT, 256, 0,0, 128, 0, 5, 0, nullptr, nullptr, nullptr, nullptr);
  launch_gemm(stream, 256, 256, BB, TT, 256, 65536,0, AN, 256, 65536,0,
              GBF, 256, 0,0, 256, 0, 9, 0, b1, mask, GCN, nullptr);
  launch_gemm(stream, BNROWS, EE, 1, GBF, 256, 0,0, W2T, 256, 0,0,
              TT, 256, 0,0, 256, 0, 5, 0, nullptr, nullptr, nullptr, nullptr);
  launch_gemm(stream, 256, 256, BB, TT, 256, 65536,0, AN, 256, 65536,0,
              GBF, 256, 0,0, 256, 0, 9, 1, b2, mask, GCN, nullptr);
  launch_gemm(stream, BNROWS, EE, 1, GBF, 256, 0,0, W3T, 256, 0,0,
              TT, 256, 0,0, 256, 0, 5, 0, nullptr, nullptr, nullptr, nullptr);
  launch_gemm(stream, 256, 256, BB, TT, 256, 65536,0, AN, 256, 65536,0,
              GBF, 256, 0,0, 256, 0, 9, 1, b3, mask, GCN, nullptr);

  // ---- LN1 ----
  ln_kernel<<<4096, 256, 0, stream>>>(GCN, ln1g, ln1b, HBF);

  // ---- attention: QKV (1 launch) -> fused flash (1) -> Y@Wo (+residual) ----
  launch_gemm(stream, BNROWS, 6144, 1, HBF, 256, 0,0, WQKVT, 256, 0,0,
              QKY, 4096, 0,0, 256, 0, 11, 0, nullptr, nullptr, nullptr, VT);
  attn_kernel<<<dim3(2, 512), 512, 0, stream>>>(QKY, VT, dist, mask);
  launch_gemm(stream, BNROWS, EE, 1, QKY, 4096, 0,0, WOT, 2048, 0,0,
              U, 256, 0,0, 2048, 0, 12, 0, bo, mask, GCN, nullptr);

  // ---- LN2 + FFN (final residual fused into FFN2 epilogue) ----
  ln_kernel<<<4096, 256, 0, stream>>>(U, ln2g, ln2b, HBF);
  launch_gemm(stream, BNROWS, FFN, 1, HBF, 256, 0,0, WF1T, 256, 0,0,
              FFB, 1024, 0,0, 256, 0, 3, 0, bf1, nullptr, nullptr, nullptr);
  launch_gemm(stream, BNROWS, EE, 1, FFB, 1024, 0,0, WF2T, 1024, 0,0,
              d_out, 256, 0,0, 1024, 0, 8, 0, bf2, mask, GCN, U);
}